// Round 8
// baseline (1362.872 us; speedup 1.0000x reference)
//
#include <hip/hip_runtime.h>
#include <math.h>

// Problem constants
static const int BSZ   = 8;
static const int SLN   = 100;
static const int NNODE = 200;
static const int NEDGE = 600;
static const int CP1N  = 111;
static const int DIM   = 128;
static const int DCN   = 64;
static const int HID   = 256;
static const int FEATN = 177;   // CP1N + DCN + 2
static const int GN    = 800;   // BS*SL
static const int MROW  = 160000; // GN*NNODE

typedef unsigned short u16;
typedef u16    u16x8  __attribute__((ext_vector_type(8)));
typedef __bf16 bf16x8 __attribute__((ext_vector_type(8)));
typedef __bf16 bf16x2 __attribute__((ext_vector_type(2)));
typedef float  f32x16 __attribute__((ext_vector_type(16)));

#if defined(__has_builtin)
# if __has_builtin(__builtin_amdgcn_fdot2_f32_bf16)
#  define HAVE_FDOT2 1
# else
#  define HAVE_FDOT2 0
# endif
#else
# define HAVE_FDOT2 0
#endif

__device__ __forceinline__ float sigf(float v){ return 1.0f/(1.0f + expf(-v)); }
__device__ __forceinline__ u16 f2bf(float f){
    union { float f; unsigned u; } v; v.f = f;
    unsigned r = v.u + 0x7FFFu + ((v.u >> 16) & 1u);
    return (u16)(r >> 16);
}
__device__ __forceinline__ float bf2f(u16 u){
    union { unsigned u; float f; } v; v.u = ((unsigned)u) << 16;
    return v.f;
}
__device__ __forceinline__ float dot2bf(unsigned w, unsigned h, float acc){
#if HAVE_FDOT2
    return __builtin_amdgcn_fdot2_f32_bf16(__builtin_bit_cast(bf16x2, w),
                                           __builtin_bit_cast(bf16x2, h), acc, false);
#else
    acc += bf2f((u16)(w & 0xffffu)) * bf2f((u16)(h & 0xffffu));
    acc += bf2f((u16)(w >> 16))     * bf2f((u16)(h >> 16));
    return acc;
#endif
}

// ---------------------------------------------------------------------------
// whhP[k2][p] = packed bf16 pair of Whh row j_orig(p) = (p&3)*256 + (p>>2)
// (quad-gate permutation: thread p of k_lstm computes gate p&3 of hidden p>>2)
// WihT[k][j] = Wih[j][k] fp32 (unpermuted; k_gi permutes on store)
__global__ void k_transpose_w(const float* __restrict__ whh, const float* __restrict__ wih,
                              unsigned* __restrict__ whhP, float* __restrict__ wihT){
    int idx = blockIdx.x*blockDim.x + threadIdx.x;
    const int total1 = 128*1024;
    if (idx < total1){
        int k2 = idx >> 10, p = idx & 1023;
        int jq = (p & 3)*256 + (p >> 2);
        u16 lo = f2bf(whh[(size_t)jq*256 + 2*k2]);
        u16 hi = f2bf(whh[(size_t)jq*256 + 2*k2 + 1]);
        whhP[(size_t)k2*1024 + p] = (unsigned)lo | ((unsigned)hi << 16);
    }
    int idx2 = idx - total1;
    const int total2 = FEATN*1024;
    if (idx2 >= 0 && idx2 < total2){
        int k = idx2 >> 10, j = idx2 & 1023;
        wihT[(size_t)k*1024 + j] = wih[(size_t)j*FEATN + k];
    }
}

// ---------------------------------------------------------------------------
// bf16 weight conversions: wih/whh (GRU, natural layout), gwT (transposed ggnn), tw (natural)
__global__ void k_convert_w(const float* __restrict__ wih, const float* __restrict__ whh,
                            const float* __restrict__ gw, const float* __restrict__ tw,
                            u16* __restrict__ wihb, u16* __restrict__ whhb,
                            u16* __restrict__ gwTb, u16* __restrict__ twb){
    int idx = blockIdx.x*blockDim.x + threadIdx.x;
    if (idx < 49152){
        wihb[idx] = f2bf(wih[idx]);
    } else if (idx < 98304){
        int t = idx - 49152;
        whhb[t] = f2bf(whh[t]);
    } else if (idx < 163840){
        int t = idx - 98304;
        int l = t >> 14, rem = t & 16383, n = rem >> 7, k = rem & 127;
        gwTb[t] = f2bf(gw[((size_t)l*128 + k)*128 + n]);
    } else if (idx < 172032){
        int t = idx - 163840;
        twb[t] = f2bf(tw[t]);
    }
}

// ---------------------------------------------------------------------------
// Per-graph CSR over dst + per-edge weight = mean(edge_embed_w[type])
__global__ void __launch_bounds__(256)
k_build_csr(const int* __restrict__ edge, const int* __restrict__ etype,
            const float* __restrict__ eembed,
            int* __restrict__ csr_src, float* __restrict__ csr_w, int* __restrict__ csr_off){
    int g = blockIdx.x; int tid = threadIdx.x;
    __shared__ float tmean[8];
    __shared__ float tpart[8][32];
    __shared__ int cnt[NNODE];
    __shared__ int offs[NNODE+1];
    __shared__ int cur[NNODE];
    {
        int ty = tid >> 5, lane = tid & 31;
        float s = 0.f;
        for (int i = lane; i < DIM; i += 32) s += eembed[ty*DIM + i];
        tpart[ty][lane] = s;
    }
    for (int i = tid; i < NNODE; i += 256) cnt[i] = 0;
    __syncthreads();
    if (tid < 8){
        float s = 0.f;
        for (int i = 0; i < 32; i++) s += tpart[tid][i];
        tmean[tid] = s / (float)DIM;
    }
    for (int e = tid; e < NEDGE; e += 256){
        int dst = edge[((size_t)g*2+1)*NEDGE + e];
        atomicAdd(&cnt[dst], 1);
    }
    __syncthreads();
    if (tid == 0){
        int run = 0;
        for (int i = 0; i < NNODE; i++){ offs[i] = run; run += cnt[i]; }
        offs[NNODE] = run;
    }
    __syncthreads();
    for (int i = tid; i < NNODE; i += 256) cur[i] = offs[i];
    for (int i = tid; i < NNODE+1; i += 256) csr_off[(size_t)g*(NNODE+1)+i] = offs[i];
    __syncthreads();
    for (int e = tid; e < NEDGE; e += 256){
        int dst = edge[((size_t)g*2+1)*NEDGE + e];
        int src = edge[((size_t)g*2+0)*NEDGE + e];
        float w = tmean[etype[(size_t)g*NEDGE + e]];
        int pos = atomicAdd(&cur[dst], 1);
        csr_src[(size_t)g*NEDGE + pos] = src;
        csr_w [(size_t)g*NEDGE + pos] = w;
    }
}

// ---------------------------------------------------------------------------
// xb = bf16(node_embed_w[node_id])
__global__ void k_gather_x(const int* __restrict__ nid, const float4* __restrict__ emb,
                           u16x8* __restrict__ xb){
    const long total = (long)MROW*16;   // 8-element chunks
    for (long c = (long)blockIdx.x*blockDim.x + threadIdx.x; c < total; c += (long)gridDim.x*blockDim.x){
        long row = c >> 4; int p = (int)(c & 15);
        float4 a = emb[(size_t)nid[row]*32 + p*2];
        float4 b = emb[(size_t)nid[row]*32 + p*2 + 1];
        u16x8 v;
        v[0]=f2bf(a.x); v[1]=f2bf(a.y); v[2]=f2bf(a.z); v[3]=f2bf(a.w);
        v[4]=f2bf(b.x); v[5]=f2bf(b.y); v[6]=f2bf(b.z); v[7]=f2bf(b.w);
        xb[c] = v;
    }
}

// ---------------------------------------------------------------------------
// MFMA m = x_g @ W with A staged coalesced in LDS (fragment order), then m
// overwrites the SAME LDS buffer (57 KB total -> 2 blocks/CU), then CSR
// scatter with 2-col-per-u32 LDS reads. One block per graph.
__global__ void __launch_bounds__(256)
k_mm_scatter(const u16* __restrict__ xb, const u16* __restrict__ gwTb_l,
             const int* __restrict__ csr_src, const float* __restrict__ csr_w,
             const int* __restrict__ csr_off, u16* __restrict__ aggb){
    __shared__ u16 smem[224*128];      // 57344 B: A-frags, later m (bf16)
    __shared__ int   e_src[NEDGE];
    __shared__ float e_w[NEDGE];
    __shared__ int   offs_s[NNODE+1];
    int g = blockIdx.x;
    int tid = threadIdx.x;
    const u16x8* xg = (const u16x8*)(xb + (size_t)g*NNODE*DIM);
    u16x8* afrag = (u16x8*)smem;       // 3584 slots: [tile7][kc8][lane64]
    for (int c = tid; c < 3584; c += 256){
        int row = c >> 4, kc8 = c & 15;
        u16x8 v = {};
        if (row < NNODE) v = xg[row*16 + kc8];
        afrag[((row>>5)*8 + (kc8>>1))*64 + (row&31) + 32*(kc8&1)] = v;
    }
    {
        const int*   srcp = csr_src + (size_t)g*NEDGE;
        const float* wp   = csr_w   + (size_t)g*NEDGE;
        const int*   off  = csr_off + (size_t)g*(NNODE+1);
        for (int i = tid; i < NEDGE; i += 256){ e_src[i] = srcp[i]; e_w[i] = wp[i]; }
        for (int i = tid; i <= NNODE; i += 256) offs_s[i] = off[i];
    }
    __syncthreads();
    int w = tid >> 6, lane = tid & 63;
    int nbase = w*32;
    int m = lane & 31, kh = lane >> 5;
    f32x16 acc[7];
    #pragma unroll
    for (int t = 0; t < 7; t++) acc[t] = (f32x16)0.f;
    const u16x8* bp = (const u16x8*)gwTb_l;
    int nrow = nbase + m;
    #pragma unroll
    for (int kc = 0; kc < 8; kc++){
        u16x8 b = bp[nrow*16 + kc*2 + kh];
        #pragma unroll
        for (int mt = 0; mt < 7; mt++){
            u16x8 a = afrag[(mt*8 + kc)*64 + lane];
            acc[mt] = __builtin_amdgcn_mfma_f32_32x32x16_bf16(
                __builtin_bit_cast(bf16x8, a), __builtin_bit_cast(bf16x8, b), acc[mt], 0, 0, 0);
        }
    }
    __syncthreads();   // all afrag reads complete before overwrite
    #pragma unroll
    for (int mt = 0; mt < 7; mt++){
        #pragma unroll
        for (int r = 0; r < 16; r++){
            int row = mt*32 + (r&3) + 8*(r>>2) + 4*kh;
            int col = nbase + m;
            smem[row*128 + col] = f2bf(acc[mt][r]);
        }
    }
    __syncthreads();
    const unsigned* m32 = (const unsigned*)smem;
    int j2 = tid & 63, rg = tid >> 6;
    unsigned* aggout = (unsigned*)(aggb + (size_t)g*NNODE*DIM);
    for (int i = 0; i < 50; i++){
        int n = rg*50 + i;
        int b0 = offs_s[n], e0 = offs_s[n+1];
        float a0 = 0.f, a1 = 0.f;
        for (int p = b0; p < e0; p++){
            unsigned mv = m32[e_src[p]*64 + j2];
            float w_ = e_w[p];
            a0 += w_ * bf2f((u16)(mv & 0xffffu));
            a1 += w_ * bf2f((u16)(mv >> 16));
        }
        aggout[(size_t)n*64 + j2] = (unsigned)f2bf(a0) | ((unsigned)f2bf(a1) << 16);
    }
}

// ---------------------------------------------------------------------------
// Fused MFMA GRU layer, M-tile 128. Grid 1250 x 512 threads.
__global__ void __launch_bounds__(512, 2)
k_gru_mfma(u16* __restrict__ xb, const u16* __restrict__ aggb,
           const u16* __restrict__ wihb, const u16* __restrict__ whhb,
           const float* __restrict__ bih, const float* __restrict__ bhh){
    __shared__ u16x8 afragA[2048];   // 128 rows: [mtile4][kc8][lane64]
    __shared__ u16x8 afragX[2048];
    int tid = threadIdx.x;
    long r0 = (long)blockIdx.x * 128;
    const u16x8* aggp = (const u16x8*)aggb;
    const u16x8* xbp  = (const u16x8*)xb;
    for (int c = tid; c < 4096; c += 512){
        int mat = c >> 11, cc = c & 2047;
        int row = cc >> 4, kc8 = cc & 15;
        u16x8 v = (mat ? xbp : aggp)[(r0 + row)*16 + kc8];
        int slot = ((row>>5)*8 + (kc8>>1))*64 + (row&31) + 32*(kc8&1);
        (mat ? afragX : afragA)[slot] = v;
    }
    __syncthreads();
    int w = tid >> 6, lane = tid & 63;
    int mtg = w >> 2;              // 0..1 -> rows mtg*64 .. mtg*64+63
    int cb  = (w & 3) * 32;        // col base within 128
    f32x16 acc0[6], acc1[6];
    #pragma unroll
    for (int t = 0; t < 6; t++){ acc0[t] = (f32x16)0.f; acc1[t] = (f32x16)0.f; }
    const u16x8* bi = (const u16x8*)wihb;
    const u16x8* bh = (const u16x8*)whhb;
    int kh = lane >> 5;
    int ncol = cb + (lane & 31);
    #pragma unroll
    for (int kc = 0; kc < 8; kc++){
        u16x8 aA0 = afragA[((2*mtg+0)*8 + kc)*64 + lane];
        u16x8 aA1 = afragA[((2*mtg+1)*8 + kc)*64 + lane];
        u16x8 aX0 = afragX[((2*mtg+0)*8 + kc)*64 + lane];
        u16x8 aX1 = afragX[((2*mtg+1)*8 + kc)*64 + lane];
        #pragma unroll
        for (int g3 = 0; g3 < 3; g3++){
            int n = g3*128 + ncol;
            u16x8 b1 = bi[n*16 + kc*2 + kh];
            u16x8 b2 = bh[n*16 + kc*2 + kh];
            acc0[g3]   = __builtin_amdgcn_mfma_f32_32x32x16_bf16(
                __builtin_bit_cast(bf16x8, aA0), __builtin_bit_cast(bf16x8, b1), acc0[g3], 0,0,0);
            acc1[g3]   = __builtin_amdgcn_mfma_f32_32x32x16_bf16(
                __builtin_bit_cast(bf16x8, aA1), __builtin_bit_cast(bf16x8, b1), acc1[g3], 0,0,0);
            acc0[3+g3] = __builtin_amdgcn_mfma_f32_32x32x16_bf16(
                __builtin_bit_cast(bf16x8, aX0), __builtin_bit_cast(bf16x8, b2), acc0[3+g3], 0,0,0);
            acc1[3+g3] = __builtin_amdgcn_mfma_f32_32x32x16_bf16(
                __builtin_bit_cast(bf16x8, aX1), __builtin_bit_cast(bf16x8, b2), acc1[3+g3], 0,0,0);
        }
    }
    int col = cb + (lane & 31);
    float bir = bih[col], biz = bih[col+128], bin = bih[col+256];
    float bhr = bhh[col], bhz = bhh[col+128], bhn = bhh[col+256];
    int kc8c = col >> 3, elc = col & 7;
    #pragma unroll
    for (int mt2 = 0; mt2 < 2; mt2++){
        const f32x16* ac = mt2 ? acc1 : acc0;
        #pragma unroll
        for (int r = 0; r < 16; r++){
            int row = mtg*64 + mt2*32 + (r&3) + 8*(r>>2) + 4*kh;
            u16x8 xv = afragX[((row>>5)*8 + (kc8c>>1))*64 + (row&31) + 32*(kc8c&1)];
            float xo = bf2f(((const u16*)&xv)[elc]);
            float rr  = sigf(ac[0][r] + bir + ac[3][r] + bhr);
            float zz  = sigf(ac[1][r] + biz + ac[4][r] + bhz);
            float nn_ = tanhf(ac[2][r] + bin + rr*(ac[5][r] + bhn));
            float xn  = (1.f - zz)*nn_ + zz*xo;
            xb[(size_t)(r0 + row)*DIM + col] = f2bf(xn);
        }
    }
}

// ---------------------------------------------------------------------------
// ggnn_out(bf16) = x @ transdim_w^T via MFMA (M x 64, K=128). Grid 1250 x 256.
__global__ void __launch_bounds__(256)
k_transdim(const u16* __restrict__ xb, const u16* __restrict__ twb, u16* __restrict__ out){
    int tid = threadIdx.x;
    int w = tid >> 6, lane = tid & 63;
    int m = lane & 31, kh = lane >> 5;
    long r0 = (long)blockIdx.x * 128;
    const u16x8* xp = (const u16x8*)xb;
    const u16x8* tp = (const u16x8*)twb;
    long rowA = r0 + w*32 + m;
    f32x16 acc[2];
    acc[0] = (f32x16)0.f; acc[1] = (f32x16)0.f;
    #pragma unroll
    for (int kc = 0; kc < 8; kc++){
        u16x8 a = xp[rowA*16 + kc*2 + kh];
        #pragma unroll
        for (int nt = 0; nt < 2; nt++){
            u16x8 b = tp[(nt*32 + m)*16 + kc*2 + kh];
            acc[nt] = __builtin_amdgcn_mfma_f32_32x32x16_bf16(
                __builtin_bit_cast(bf16x8, a), __builtin_bit_cast(bf16x8, b), acc[nt], 0,0,0);
        }
    }
    #pragma unroll
    for (int nt = 0; nt < 2; nt++){
        #pragma unroll
        for (int r = 0; r < 16; r++){
            int row = w*32 + (r&3) + 8*(r>>2) + 4*kh;
            int col = nt*32 + m;
            out[(r0 + row)*DCN + col] = f2bf(acc[nt][r]);
        }
    }
}

// ---------------------------------------------------------------------------
// Attention + lstm_in assembly. One block per g. bf16 gout input; wave-shuffle
// reductions (3 barriers per active concept instead of ~18 barrier-tree syncs).
__global__ void __launch_bounds__(256)
k_attention(const u16* __restrict__ gout, const float* __restrict__ cemb,
            const float* __restrict__ cid, const float* __restrict__ conc,
            const float* __restrict__ curres, float* __restrict__ lstm_in){
    int g = blockIdx.x; int tid = threadIdx.x;
    int lane = tid & 63, wv = tid >> 6;
    __shared__ float gg[NNODE*65];
    __shared__ float ce_s[CP1N];
    __shared__ float sc[256];
    __shared__ float wredA[4];
    __shared__ float wredB[4];
    __shared__ float part[4][DCN];
    __shared__ float oacc[DCN];
    __shared__ float num_s;
    if (tid < CP1N) ce_s[tid] = cemb[(size_t)g*CP1N + tid];
    if (tid < DCN) oacc[tid] = 0.f;
    for (int i = tid; i < NNODE*DCN; i += 256){
        int n = i >> 6, d = i & 63;
        gg[n*65 + d] = bf2f(gout[(size_t)g*NNODE*DCN + i]);
    }
    {
        float v = (tid < CP1N) ? cid[(size_t)g*CP1N + tid] : 0.f;
        #pragma unroll
        for (int m2 = 32; m2; m2 >>= 1) v += __shfl_xor(v, m2);
        if (lane == 0) wredA[wv] = v;
    }
    __syncthreads();
    if (tid == 0){
        float nm = wredA[0]+wredA[1]+wredA[2]+wredA[3];
        num_s = (nm == 0.f) ? 1.f : nm;
    }
    __syncthreads();
    for (int c = 0; c < CP1N; c++){
        float ce = ce_s[c];
        if (ce == 0.f) continue;          // uniform across block
        const float* qc = conc + c*DCN;   // wave-uniform address -> scalar loads
        float s = -1e30f;
        if (tid < NNODE){
            float a_ = 0.f;
            const float* gr_ = &gg[tid*65];
            #pragma unroll 16
            for (int d = 0; d < DCN; d++) a_ += qc[d] * gr_[d];
            s = ce * a_;
        }
        float m_ = s;
        #pragma unroll
        for (int m2 = 32; m2; m2 >>= 1) m_ = fmaxf(m_, __shfl_xor(m_, m2));
        if (lane == 0) wredA[wv] = m_;
        __syncthreads();                                    // barrier 1
        float mx = fmaxf(fmaxf(wredA[0], wredA[1]), fmaxf(wredA[2], wredA[3]));
        float e = (tid < NNODE) ? expf(s - mx) : 0.f;
        sc[tid] = e;
        float sum_ = e;
        #pragma unroll
        for (int m2 = 32; m2; m2 >>= 1) sum_ += __shfl_xor(sum_, m2);
        if (lane == 0) wredB[wv] = sum_;
        __syncthreads();                                    // barrier 2
        float inv = ce / (wredB[0]+wredB[1]+wredB[2]+wredB[3]);
        float pa = 0.f;
        for (int n = wv; n < NNODE; n += 4) pa += sc[n] * gg[n*65 + lane];
        part[wv][lane] = pa;
        __syncthreads();                                    // barrier 3
        if (tid < DCN) oacc[tid] += inv * (part[0][tid] + part[1][tid] + part[2][tid] + part[3][tid]);
    }
    __syncthreads();
    if (tid < FEATN){
        float v;
        if      (tid < CP1N)       v = ce_s[tid];
        else if (tid < CP1N+DCN)   v = oacc[tid-CP1N] / num_s;
        else                       v = curres[(size_t)g*2 + (tid-CP1N-DCN)];
        lstm_in[(size_t)g*FEATN + tid] = v;
    }
}

// ---------------------------------------------------------------------------
// gi_all = lstm_in @ Wih^T + (bih + bhh), stored QUAD-PERMUTED for k_lstm:
// value for weight row j lands at position (j&255)*4 + (j>>8).
__global__ void __launch_bounds__(256)
k_gi(const float* __restrict__ lstm_in, const float* __restrict__ wihT,
     const float* __restrict__ bih, const float* __restrict__ bhh, float* __restrict__ gi){
    int rb = blockIdx.x;   // 100 blocks of 8 rows
    int jb = blockIdx.y;   // 4
    int tid = threadIdx.x;
    __shared__ float in_s[8][FEATN];
    for (int i = tid; i < 8*FEATN; i += 256){ int r = i/FEATN, k = i%FEATN; in_s[r][k] = lstm_in[((size_t)rb*8+r)*FEATN + k]; }
    __syncthreads();
    int j = jb*256 + tid;
    float acc[8];
    #pragma unroll
    for (int i = 0; i < 8; i++) acc[i] = 0.f;
    for (int k = 0; k < FEATN; k++){
        float w = wihT[(size_t)k*1024 + j];
        #pragma unroll
        for (int i = 0; i < 8; i++) acc[i] += in_s[i][k] * w;
    }
    float b = bih[j] + bhh[j];
    int jp = (j & 255)*4 + (j >> 8);
    #pragma unroll
    for (int i = 0; i < 8; i++) gi[((size_t)rb*8+i)*1024 + jp] = acc[i] + b;
}

// ---------------------------------------------------------------------------
// Sequential LSTM, quad-gate mapping: thread tid computes gate tid&3 of hidden
// tid>>2 (all 4 gates of a hidden unit in ONE quad). Gate assembly via 4
// intra-quad shuffles; c/h computed redundantly in all lanes -> elementwise is
// parallel across all 16 waves; ONE barrier per step with double-buffered h.
static const int WREG = 104;
static const int WL4  = 6;    // 24 pairs = 6 uint4 groups (pairs 104..127)

__global__ void __launch_bounds__(1024)
__attribute__((amdgpu_waves_per_eu(4,4)))
k_lstm(const float* __restrict__ gi, const unsigned* __restrict__ whhP, float* __restrict__ out){
    int b = blockIdx.x; int tid = threadIdx.x;
    __shared__ uint4 ldsw4[WL4][1024];       // 96 KB
    __shared__ unsigned hbuf[2][128];        // double-buffered packed bf16 h
    unsigned wreg[WREG];
    #pragma unroll
    for (int i = 0; i < WREG; i++) wreg[i] = whhP[(size_t)i*1024 + tid];
    #pragma unroll
    for (int q = 0; q < WL4; q++){
        uint4 v;
        v.x = whhP[(size_t)(WREG + 4*q + 0)*1024 + tid];
        v.y = whhP[(size_t)(WREG + 4*q + 1)*1024 + tid];
        v.z = whhP[(size_t)(WREG + 4*q + 2)*1024 + tid];
        v.w = whhP[(size_t)(WREG + 4*q + 3)*1024 + tid];
        ldsw4[q][tid] = v;
    }
    if (tid < 128) hbuf[0][tid] = 0u;
    float c_reg = 0.f;
    int lane = tid & 63;
    int hq = tid >> 2;        // hidden unit owned by this quad
    __syncthreads();
    unsigned hv0 = hbuf[0][lane];
    unsigned hv1 = hbuf[0][64 + lane];
    float giv = gi[(size_t)b*SLN*1024 + tid];
    for (int t = 0; t < SLN; t++){
        float acc0 = giv, acc1 = 0.f;
        if (t+1 < SLN) giv = gi[((size_t)b*SLN + t + 1)*1024 + tid];
        #pragma unroll
        for (int p = 0; p < 64; p += 2){
            unsigned hpa = (unsigned)__builtin_amdgcn_readlane((int)hv0, p);
            unsigned hpb = (unsigned)__builtin_amdgcn_readlane((int)hv0, p+1);
            acc0 = dot2bf(wreg[p],   hpa, acc0);
            acc1 = dot2bf(wreg[p+1], hpb, acc1);
        }
        #pragma unroll
        for (int p = 64; p < WREG; p += 2){
            unsigned hpa = (unsigned)__builtin_amdgcn_readlane((int)hv1, p - 64);
            unsigned hpb = (unsigned)__builtin_amdgcn_readlane((int)hv1, p - 63);
            acc0 = dot2bf(wreg[p],   hpa, acc0);
            acc1 = dot2bf(wreg[p+1], hpb, acc1);
        }
        #pragma unroll
        for (int q = 0; q < WL4; q++){
            uint4 wv = ldsw4[q][tid];
            int base = WREG + 4*q - 64;
            unsigned h0 = (unsigned)__builtin_amdgcn_readlane((int)hv1, base + 0);
            unsigned h1 = (unsigned)__builtin_amdgcn_readlane((int)hv1, base + 1);
            unsigned h2 = (unsigned)__builtin_amdgcn_readlane((int)hv1, base + 2);
            unsigned h3 = (unsigned)__builtin_amdgcn_readlane((int)hv1, base + 3);
            acc0 = dot2bf(wv.x, h0, acc0);
            acc1 = dot2bf(wv.y, h1, acc1);
            acc0 = dot2bf(wv.z, h2, acc0);
            acc1 = dot2bf(wv.w, h3, acc1);
        }
        float gval = acc0 + acc1;
        // assemble the quad's 4 gates in every lane (width-4 shuffles)
        float v0 = __shfl(gval, 0, 4);
        float v1 = __shfl(gval, 1, 4);
        float v2 = __shfl(gval, 2, 4);
        float v3 = __shfl(gval, 3, 4);
        float i_ = sigf(v0);
        float f_ = sigf(v1);
        float g_ = tanhf(v2);
        float o_ = sigf(v3);
        c_reg = f_*c_reg + i_*g_;
        float h = o_*tanhf(c_reg);
        int nb = (t+1) & 1;
        if ((tid & 3) == 0){
            out[((size_t)b*SLN + t)*HID + hq] = h;
            ((u16*)hbuf[nb])[hq] = f2bf(h);
        }
        __syncthreads();
        hv0 = hbuf[nb][lane];
        hv1 = hbuf[nb][64 + lane];
    }
}

// ---------------------------------------------------------------------------
// pred + masked BCE per row; outputs sigmoid(fp), ft; atomics for loss sums.
__global__ void __launch_bounds__(128)
k_final(const float* __restrict__ lstm_out, const float* __restrict__ pw, const float* __restrict__ pb,
        const float* __restrict__ tc, const float* __restrict__ result,
        float* __restrict__ out, float* __restrict__ lacc){
    int row = blockIdx.x; int tid = threadIdx.x;
    __shared__ __align__(16) float h_s[HID];
    __shared__ float redv[128], redn[128];
    h_s[tid]       = lstm_out[(size_t)row*HID + tid];
    h_s[tid + 128] = lstm_out[(size_t)row*HID + tid + 128];
    __syncthreads();
    float v = 0.f, n = 0.f;
    if (tid < CP1N){
        float acc = pb[tid];
        const float4* wr = (const float4*)(pw + (size_t)tid*HID);
        const float4* hp = (const float4*)h_s;
        #pragma unroll 8
        for (int k4 = 0; k4 < 64; k4++){
            float4 w = wr[k4]; float4 h4 = hp[k4];
            acc += h4.x*w.x + h4.y*w.y + h4.z*w.z + h4.w*w.w;
        }
        float t = tc[(size_t)row*CP1N + tid];
        v = acc*t; n = t;
    }
    redv[tid] = v; redn[tid] = n;
    __syncthreads();
    for (int s = 64; s > 0; s >>= 1){
        if (tid < s){ redv[tid] += redv[tid+s]; redn[tid] += redn[tid+s]; }
        __syncthreads();
    }
    if (tid == 0){
        float nc = redn[0];
        bool mask = nc > 0.f;
        float fp = redv[0] / (mask ? nc : 1.f);
        float ft = result[row];
        float bce = fmaxf(fp, 0.f) - fp*ft + log1pf(expf(-fabsf(fp)));
        out[1 + row]      = 1.f/(1.f + expf(-fp));
        out[1 + GN + row] = ft;
        if (mask){ atomicAdd(&lacc[0], bce); atomicAdd(&lacc[1], 1.f); }
    }
}

__global__ void k_loss_final(const float* __restrict__ lacc, float* __restrict__ out){
    out[0] = lacc[0] / fmaxf(lacc[1], 1.f);
}

// ---------------------------------------------------------------------------
extern "C" void kernel_launch(void* const* d_in, const int* in_sizes, int n_in,
                              void* d_out, int out_size, void* d_ws, size_t ws_size,
                              hipStream_t stream) {
    const float* c_id        = (const float*)d_in[1];
    const int*   node_id     = (const int*)  d_in[2];
    const int*   edge        = (const int*)  d_in[3];
    const int*   etype       = (const int*)  d_in[4];
    const float* target_c    = (const float*)d_in[5];
    const float* result      = (const float*)d_in[6];
    const float* c_embed     = (const float*)d_in[7];
    const float* cur_result  = (const float*)d_in[8];
    const float* node_emb_w  = (const float*)d_in[9];
    const float* edge_emb_w  = (const float*)d_in[10];
    const float* ggnn_w      = (const float*)d_in[11];
    const float* gru_w_ih    = (const float*)d_in[12];
    const float* gru_w_hh    = (const float*)d_in[13];
    const float* gru_b_ih    = (const float*)d_in[14];
    const float* gru_b_hh    = (const float*)d_in[15];
    const float* transdim_w  = (const float*)d_in[16];
    const float* concept     = (const float*)d_in[17];
    const float* lstm_w_ih   = (const float*)d_in[18];
    const float* lstm_w_hh   = (const float*)d_in[19];
    const float* lstm_b_ih   = (const float*)d_in[20];
    const float* lstm_b_hh   = (const float*)d_in[21];
    const float* pred_w      = (const float*)d_in[22];
    const float* pred_b      = (const float*)d_in[23];
    float* out = (float*)d_out;

    char* ws = (char*)d_ws;
    size_t off = 0;
    auto alloc = [&](size_t bytes) -> void* {
        void* p = ws + off;
        off += (bytes + 255) & ~(size_t)255;
        return p;
    };
    u16*      xb       = (u16*)     alloc((size_t)MROW*DIM*2);
    u16*      aggb     = (u16*)     alloc((size_t)MROW*DIM*2);
    int*      csr_src  = (int*)     alloc((size_t)GN*NEDGE*4);
    float*    csr_w    = (float*)   alloc((size_t)GN*NEDGE*4);
    int*      csr_off  = (int*)     alloc((size_t)GN*(NNODE+1)*4);
    float*    lstm_in  = (float*)   alloc((size_t)GN*FEATN*4);
    float*    gi       = (float*)   alloc((size_t)GN*1024*4);
    unsigned* whhP     = (unsigned*)alloc((size_t)128*1024*4);
    float*    wihT     = (float*)   alloc((size_t)FEATN*1024*4);
    float*    lstm_out = (float*)   alloc((size_t)GN*HID*4);
    u16*      wihb     = (u16*)     alloc((size_t)384*128*2);
    u16*      whhb     = (u16*)     alloc((size_t)384*128*2);
    u16*      gwTb     = (u16*)     alloc((size_t)4*128*128*2);
    u16*      twb      = (u16*)     alloc((size_t)DCN*DIM*2);
    float*    lacc     = (float*)   alloc(256);
    u16*      ggnn_out = (u16*)aggb;   // aggb dead after layer 4; reuse for bf16 (M x 64)

    hipMemsetAsync(lacc, 0, 8, stream);
    {
        int total = 128*1024 + FEATN*1024;
        k_transpose_w<<<(total + 255)/256, 256, 0, stream>>>(lstm_w_hh, lstm_w_ih, whhP, wihT);
    }
    k_convert_w<<<672, 256, 0, stream>>>(gru_w_ih, gru_w_hh, ggnn_w, transdim_w, wihb, whhb, gwTb, twb);
    k_build_csr<<<GN, 256, 0, stream>>>(edge, etype, edge_emb_w, csr_src, csr_w, csr_off);
    k_gather_x<<<4096, 256, 0, stream>>>(node_id, (const float4*)node_emb_w, (u16x8*)xb);
    for (int l = 0; l < 4; l++){
        k_mm_scatter<<<GN, 256, 0, stream>>>(xb, gwTb + (size_t)l*DIM*DIM,
                                             csr_src, csr_w, csr_off, aggb);
        k_gru_mfma<<<MROW/128, 512, 0, stream>>>(xb, aggb, wihb, whhb, gru_b_ih, gru_b_hh);
    }
    k_transdim<<<MROW/128, 256, 0, stream>>>(xb, twb, ggnn_out);
    k_attention<<<GN, 256, 0, stream>>>(ggnn_out, c_embed, c_id, concept, cur_result, lstm_in);
    k_gi<<<dim3(100, 4), 256, 0, stream>>>(lstm_in, wihT, lstm_b_ih, lstm_b_hh, gi);
    k_lstm<<<BSZ, 1024, 0, stream>>>(gi, whhP, lstm_out);
    k_final<<<GN, 128, 0, stream>>>(lstm_out, pred_w, pred_b, target_c, result, out, lacc);
    k_loss_final<<<1, 1, 0, stream>>>(lacc, out);
}

// Round 9
// 1313.543 us; speedup vs baseline: 1.0376x; 1.0376x over previous
//
#include <hip/hip_runtime.h>
#include <math.h>

// Problem constants
static const int BSZ   = 8;
static const int SLN   = 100;
static const int NNODE = 200;
static const int NEDGE = 600;
static const int CP1N  = 111;
static const int DIM   = 128;
static const int DCN   = 64;
static const int HID   = 256;
static const int FEATN = 177;   // CP1N + DCN + 2
static const int GN    = 800;   // BS*SL
static const int MROW  = 160000; // GN*NNODE

typedef unsigned short u16;
typedef u16    u16x8  __attribute__((ext_vector_type(8)));
typedef __bf16 bf16x8 __attribute__((ext_vector_type(8)));
typedef __bf16 bf16x2 __attribute__((ext_vector_type(2)));
typedef float  f32x16 __attribute__((ext_vector_type(16)));

#if defined(__has_builtin)
# if __has_builtin(__builtin_amdgcn_fdot2_f32_bf16)
#  define HAVE_FDOT2 1
# else
#  define HAVE_FDOT2 0
# endif
#else
# define HAVE_FDOT2 0
#endif

__device__ __forceinline__ float sigf(float v){ return 1.0f/(1.0f + expf(-v)); }
__device__ __forceinline__ u16 f2bf(float f){
    union { float f; unsigned u; } v; v.f = f;
    unsigned r = v.u + 0x7FFFu + ((v.u >> 16) & 1u);
    return (u16)(r >> 16);
}
__device__ __forceinline__ float bf2f(u16 u){
    union { unsigned u; float f; } v; v.u = ((unsigned)u) << 16;
    return v.f;
}
__device__ __forceinline__ float dot2bf(unsigned w, unsigned h, float acc){
#if HAVE_FDOT2
    return __builtin_amdgcn_fdot2_f32_bf16(__builtin_bit_cast(bf16x2, w),
                                           __builtin_bit_cast(bf16x2, h), acc, false);
#else
    acc += bf2f((u16)(w & 0xffffu)) * bf2f((u16)(h & 0xffffu));
    acc += bf2f((u16)(w >> 16))     * bf2f((u16)(h >> 16));
    return acc;
#endif
}

// A-fragment LDS slot with XOR bank swizzle: for (row, kc8) the element lives at
// (tile*8 + kcq)*64 + (pos ^ kcq), pos = (row&31) + 32*(kc8&1), kcq = kc8>>1.
// Read side: fragment (mt, kc) for lane l is at (mt*8+kc)*64 + (l ^ kc).
// Without the XOR, the 16 same-row writers hit one bank (16-way ds_write conflict).
__device__ __forceinline__ int afrag_slot(int row, int kc8){
    int kcq = kc8 >> 1;
    int pos = (row & 31) + 32*(kc8 & 1);
    return ((row >> 5)*8 + kcq)*64 + (pos ^ kcq);
}

// ---------------------------------------------------------------------------
// whhP[k2][j] = packed bf16 pair (Whh[j][2k2], Whh[j][2k2+1]);  WihT[k][j] = Wih[j][k] fp32
__global__ void k_transpose_w(const float* __restrict__ whh, const float* __restrict__ wih,
                              unsigned* __restrict__ whhP, float* __restrict__ wihT){
    int idx = blockIdx.x*blockDim.x + threadIdx.x;
    const int total1 = 128*1024;
    if (idx < total1){
        int k2 = idx >> 10, j = idx & 1023;
        u16 lo = f2bf(whh[(size_t)j*256 + 2*k2]);
        u16 hi = f2bf(whh[(size_t)j*256 + 2*k2 + 1]);
        whhP[(size_t)k2*1024 + j] = (unsigned)lo | ((unsigned)hi << 16);
    }
    int idx2 = idx - total1;
    const int total2 = FEATN*1024;
    if (idx2 >= 0 && idx2 < total2){
        int k = idx2 >> 10, j = idx2 & 1023;
        wihT[(size_t)k*1024 + j] = wih[(size_t)j*FEATN + k];
    }
}

// ---------------------------------------------------------------------------
// bf16 weight conversions: wih/whh (GRU, natural layout), gwT (transposed ggnn), tw (natural)
__global__ void k_convert_w(const float* __restrict__ wih, const float* __restrict__ whh,
                            const float* __restrict__ gw, const float* __restrict__ tw,
                            u16* __restrict__ wihb, u16* __restrict__ whhb,
                            u16* __restrict__ gwTb, u16* __restrict__ twb){
    int idx = blockIdx.x*blockDim.x + threadIdx.x;
    if (idx < 49152){
        wihb[idx] = f2bf(wih[idx]);
    } else if (idx < 98304){
        int t = idx - 49152;
        whhb[t] = f2bf(whh[t]);
    } else if (idx < 163840){
        int t = idx - 98304;
        int l = t >> 14, rem = t & 16383, n = rem >> 7, k = rem & 127;
        gwTb[t] = f2bf(gw[((size_t)l*128 + k)*128 + n]);
    } else if (idx < 172032){
        int t = idx - 163840;
        twb[t] = f2bf(tw[t]);
    }
}

// ---------------------------------------------------------------------------
// Per-graph CSR over dst + per-edge weight = mean(edge_embed_w[type])
__global__ void __launch_bounds__(256)
k_build_csr(const int* __restrict__ edge, const int* __restrict__ etype,
            const float* __restrict__ eembed,
            int* __restrict__ csr_src, float* __restrict__ csr_w, int* __restrict__ csr_off){
    int g = blockIdx.x; int tid = threadIdx.x;
    __shared__ float tmean[8];
    __shared__ float tpart[8][32];
    __shared__ int cnt[NNODE];
    __shared__ int offs[NNODE+1];
    __shared__ int cur[NNODE];
    {
        int ty = tid >> 5, lane = tid & 31;
        float s = 0.f;
        for (int i = lane; i < DIM; i += 32) s += eembed[ty*DIM + i];
        tpart[ty][lane] = s;
    }
    for (int i = tid; i < NNODE; i += 256) cnt[i] = 0;
    __syncthreads();
    if (tid < 8){
        float s = 0.f;
        for (int i = 0; i < 32; i++) s += tpart[tid][i];
        tmean[tid] = s / (float)DIM;
    }
    for (int e = tid; e < NEDGE; e += 256){
        int dst = edge[((size_t)g*2+1)*NEDGE + e];
        atomicAdd(&cnt[dst], 1);
    }
    __syncthreads();
    if (tid == 0){
        int run = 0;
        for (int i = 0; i < NNODE; i++){ offs[i] = run; run += cnt[i]; }
        offs[NNODE] = run;
    }
    __syncthreads();
    for (int i = tid; i < NNODE; i += 256) cur[i] = offs[i];
    for (int i = tid; i < NNODE+1; i += 256) csr_off[(size_t)g*(NNODE+1)+i] = offs[i];
    __syncthreads();
    for (int e = tid; e < NEDGE; e += 256){
        int dst = edge[((size_t)g*2+1)*NEDGE + e];
        int src = edge[((size_t)g*2+0)*NEDGE + e];
        float w = tmean[etype[(size_t)g*NEDGE + e]];
        int pos = atomicAdd(&cur[dst], 1);
        csr_src[(size_t)g*NEDGE + pos] = src;
        csr_w [(size_t)g*NEDGE + pos] = w;
    }
}

// ---------------------------------------------------------------------------
// xb = bf16(node_embed_w[node_id])
__global__ void k_gather_x(const int* __restrict__ nid, const float4* __restrict__ emb,
                           u16x8* __restrict__ xb){
    const long total = (long)MROW*16;   // 8-element chunks
    for (long c = (long)blockIdx.x*blockDim.x + threadIdx.x; c < total; c += (long)gridDim.x*blockDim.x){
        long row = c >> 4; int p = (int)(c & 15);
        float4 a = emb[(size_t)nid[row]*32 + p*2];
        float4 b = emb[(size_t)nid[row]*32 + p*2 + 1];
        u16x8 v;
        v[0]=f2bf(a.x); v[1]=f2bf(a.y); v[2]=f2bf(a.z); v[3]=f2bf(a.w);
        v[4]=f2bf(b.x); v[5]=f2bf(b.y); v[6]=f2bf(b.z); v[7]=f2bf(b.w);
        xb[c] = v;
    }
}

// ---------------------------------------------------------------------------
// MFMA m = x_g @ W with A staged coalesced in LDS (swizzled fragment order),
// then m overwrites the SAME LDS buffer, then CSR scatter (2 cols per u32 read).
__global__ void __launch_bounds__(256)
k_mm_scatter(const u16* __restrict__ xb, const u16* __restrict__ gwTb_l,
             const int* __restrict__ csr_src, const float* __restrict__ csr_w,
             const int* __restrict__ csr_off, u16* __restrict__ aggb){
    __shared__ u16 smem[224*128];      // 57344 B: A-frags, later m (bf16)
    __shared__ int   e_src[NEDGE];
    __shared__ float e_w[NEDGE];
    __shared__ int   offs_s[NNODE+1];
    int g = blockIdx.x;
    int tid = threadIdx.x;
    const u16x8* xg = (const u16x8*)(xb + (size_t)g*NNODE*DIM);
    u16x8* afrag = (u16x8*)smem;       // 3584 slots: [tile7][kcq8][pos^kcq]
    for (int c = tid; c < 3584; c += 256){
        int row = c >> 4, kc8 = c & 15;
        u16x8 v = {};
        if (row < NNODE) v = xg[row*16 + kc8];
        afrag[afrag_slot(row, kc8)] = v;
    }
    {
        const int*   srcp = csr_src + (size_t)g*NEDGE;
        const float* wp   = csr_w   + (size_t)g*NEDGE;
        const int*   off  = csr_off + (size_t)g*(NNODE+1);
        for (int i = tid; i < NEDGE; i += 256){ e_src[i] = srcp[i]; e_w[i] = wp[i]; }
        for (int i = tid; i <= NNODE; i += 256) offs_s[i] = off[i];
    }
    __syncthreads();
    int w = tid >> 6, lane = tid & 63;
    int nbase = w*32;
    int m = lane & 31, kh = lane >> 5;
    f32x16 acc[7];
    #pragma unroll
    for (int t = 0; t < 7; t++) acc[t] = (f32x16)0.f;
    const u16x8* bp = (const u16x8*)gwTb_l;
    int nrow = nbase + m;
    #pragma unroll
    for (int kc = 0; kc < 8; kc++){
        u16x8 b = bp[nrow*16 + kc*2 + kh];
        #pragma unroll
        for (int mt = 0; mt < 7; mt++){
            u16x8 a = afrag[(mt*8 + kc)*64 + (lane ^ kc)];
            acc[mt] = __builtin_amdgcn_mfma_f32_32x32x16_bf16(
                __builtin_bit_cast(bf16x8, a), __builtin_bit_cast(bf16x8, b), acc[mt], 0, 0, 0);
        }
    }
    __syncthreads();   // all afrag reads complete before overwrite
    #pragma unroll
    for (int mt = 0; mt < 7; mt++){
        #pragma unroll
        for (int r = 0; r < 16; r++){
            int row = mt*32 + (r&3) + 8*(r>>2) + 4*kh;
            int col = nbase + m;
            smem[row*128 + col] = f2bf(acc[mt][r]);
        }
    }
    __syncthreads();
    const unsigned* m32 = (const unsigned*)smem;
    int j2 = tid & 63, rg = tid >> 6;
    unsigned* aggout = (unsigned*)(aggb + (size_t)g*NNODE*DIM);
    for (int i = 0; i < 50; i++){
        int n = rg*50 + i;
        int b0 = offs_s[n], e0 = offs_s[n+1];
        float a0 = 0.f, a1 = 0.f;
        for (int p = b0; p < e0; p++){
            unsigned mv = m32[e_src[p]*64 + j2];
            float w_ = e_w[p];
            a0 += w_ * bf2f((u16)(mv & 0xffffu));
            a1 += w_ * bf2f((u16)(mv >> 16));
        }
        aggout[(size_t)n*64 + j2] = (unsigned)f2bf(a0) | ((unsigned)f2bf(a1) << 16);
    }
}

// ---------------------------------------------------------------------------
// Fused MFMA GRU layer, M-tile 128. Grid 1250 x 512 threads. Swizzled staging.
__global__ void __launch_bounds__(512, 2)
k_gru_mfma(u16* __restrict__ xb, const u16* __restrict__ aggb,
           const u16* __restrict__ wihb, const u16* __restrict__ whhb,
           const float* __restrict__ bih, const float* __restrict__ bhh){
    __shared__ u16x8 afragA[2048];   // 128 rows: [mtile4][kcq8][pos^kcq]
    __shared__ u16x8 afragX[2048];
    int tid = threadIdx.x;
    long r0 = (long)blockIdx.x * 128;
    const u16x8* aggp = (const u16x8*)aggb;
    const u16x8* xbp  = (const u16x8*)xb;
    for (int c = tid; c < 4096; c += 512){
        int mat = c >> 11, cc = c & 2047;
        int row = cc >> 4, kc8 = cc & 15;
        u16x8 v = (mat ? xbp : aggp)[(r0 + row)*16 + kc8];
        (mat ? afragX : afragA)[afrag_slot(row, kc8)] = v;
    }
    __syncthreads();
    int w = tid >> 6, lane = tid & 63;
    int mtg = w >> 2;              // 0..1 -> rows mtg*64 .. mtg*64+63
    int cb  = (w & 3) * 32;        // col base within 128
    f32x16 acc0[6], acc1[6];
    #pragma unroll
    for (int t = 0; t < 6; t++){ acc0[t] = (f32x16)0.f; acc1[t] = (f32x16)0.f; }
    const u16x8* bi = (const u16x8*)wihb;
    const u16x8* bh = (const u16x8*)whhb;
    int kh = lane >> 5;
    int ncol = cb + (lane & 31);
    #pragma unroll
    for (int kc = 0; kc < 8; kc++){
        int lx = lane ^ kc;
        u16x8 aA0 = afragA[((2*mtg+0)*8 + kc)*64 + lx];
        u16x8 aA1 = afragA[((2*mtg+1)*8 + kc)*64 + lx];
        u16x8 aX0 = afragX[((2*mtg+0)*8 + kc)*64 + lx];
        u16x8 aX1 = afragX[((2*mtg+1)*8 + kc)*64 + lx];
        #pragma unroll
        for (int g3 = 0; g3 < 3; g3++){
            int n = g3*128 + ncol;
            u16x8 b1 = bi[n*16 + kc*2 + kh];
            u16x8 b2 = bh[n*16 + kc*2 + kh];
            acc0[g3]   = __builtin_amdgcn_mfma_f32_32x32x16_bf16(
                __builtin_bit_cast(bf16x8, aA0), __builtin_bit_cast(bf16x8, b1), acc0[g3], 0,0,0);
            acc1[g3]   = __builtin_amdgcn_mfma_f32_32x32x16_bf16(
                __builtin_bit_cast(bf16x8, aA1), __builtin_bit_cast(bf16x8, b1), acc1[g3], 0,0,0);
            acc0[3+g3] = __builtin_amdgcn_mfma_f32_32x32x16_bf16(
                __builtin_bit_cast(bf16x8, aX0), __builtin_bit_cast(bf16x8, b2), acc0[3+g3], 0,0,0);
            acc1[3+g3] = __builtin_amdgcn_mfma_f32_32x32x16_bf16(
                __builtin_bit_cast(bf16x8, aX1), __builtin_bit_cast(bf16x8, b2), acc1[3+g3], 0,0,0);
        }
    }
    int col = cb + (lane & 31);
    float bir = bih[col], biz = bih[col+128], bin = bih[col+256];
    float bhr = bhh[col], bhz = bhh[col+128], bhn = bhh[col+256];
    int kc8c = col >> 3, elc = col & 7;
    #pragma unroll
    for (int mt2 = 0; mt2 < 2; mt2++){
        const f32x16* ac = mt2 ? acc1 : acc0;
        #pragma unroll
        for (int r = 0; r < 16; r++){
            int row = mtg*64 + mt2*32 + (r&3) + 8*(r>>2) + 4*kh;
            u16x8 xv = afragX[afrag_slot(row, kc8c)];
            float xo = bf2f(((const u16*)&xv)[elc]);
            float rr  = sigf(ac[0][r] + bir + ac[3][r] + bhr);
            float zz  = sigf(ac[1][r] + biz + ac[4][r] + bhz);
            float nn_ = tanhf(ac[2][r] + bin + rr*(ac[5][r] + bhn));
            float xn  = (1.f - zz)*nn_ + zz*xo;
            xb[(size_t)(r0 + row)*DIM + col] = f2bf(xn);
        }
    }
}

// ---------------------------------------------------------------------------
// ggnn_out(bf16) = x @ transdim_w^T via MFMA (M x 64, K=128). Grid 1250 x 256.
__global__ void __launch_bounds__(256)
k_transdim(const u16* __restrict__ xb, const u16* __restrict__ twb, u16* __restrict__ out){
    int tid = threadIdx.x;
    int w = tid >> 6, lane = tid & 63;
    int m = lane & 31, kh = lane >> 5;
    long r0 = (long)blockIdx.x * 128;
    const u16x8* xp = (const u16x8*)xb;
    const u16x8* tp = (const u16x8*)twb;
    long rowA = r0 + w*32 + m;
    f32x16 acc[2];
    acc[0] = (f32x16)0.f; acc[1] = (f32x16)0.f;
    #pragma unroll
    for (int kc = 0; kc < 8; kc++){
        u16x8 a = xp[rowA*16 + kc*2 + kh];
        #pragma unroll
        for (int nt = 0; nt < 2; nt++){
            u16x8 b = tp[(nt*32 + m)*16 + kc*2 + kh];
            acc[nt] = __builtin_amdgcn_mfma_f32_32x32x16_bf16(
                __builtin_bit_cast(bf16x8, a), __builtin_bit_cast(bf16x8, b), acc[nt], 0,0,0);
        }
    }
    #pragma unroll
    for (int nt = 0; nt < 2; nt++){
        #pragma unroll
        for (int r = 0; r < 16; r++){
            int row = w*32 + (r&3) + 8*(r>>2) + 4*kh;
            int col = nt*32 + m;
            out[(r0 + row)*DCN + col] = f2bf(acc[nt][r]);
        }
    }
}

// ---------------------------------------------------------------------------
// Attention + lstm_in assembly. One block per g. bf16 gout input; wave-shuffle
// reductions (3 barriers per active concept).
__global__ void __launch_bounds__(256)
k_attention(const u16* __restrict__ gout, const float* __restrict__ cemb,
            const float* __restrict__ cid, const float* __restrict__ conc,
            const float* __restrict__ curres, float* __restrict__ lstm_in){
    int g = blockIdx.x; int tid = threadIdx.x;
    int lane = tid & 63, wv = tid >> 6;
    __shared__ float gg[NNODE*65];
    __shared__ float ce_s[CP1N];
    __shared__ float sc[256];
    __shared__ float wredA[4];
    __shared__ float wredB[4];
    __shared__ float part[4][DCN];
    __shared__ float oacc[DCN];
    __shared__ float num_s;
    if (tid < CP1N) ce_s[tid] = cemb[(size_t)g*CP1N + tid];
    if (tid < DCN) oacc[tid] = 0.f;
    for (int i = tid; i < NNODE*DCN; i += 256){
        int n = i >> 6, d = i & 63;
        gg[n*65 + d] = bf2f(gout[(size_t)g*NNODE*DCN + i]);
    }
    {
        float v = (tid < CP1N) ? cid[(size_t)g*CP1N + tid] : 0.f;
        #pragma unroll
        for (int m2 = 32; m2; m2 >>= 1) v += __shfl_xor(v, m2);
        if (lane == 0) wredA[wv] = v;
    }
    __syncthreads();
    if (tid == 0){
        float nm = wredA[0]+wredA[1]+wredA[2]+wredA[3];
        num_s = (nm == 0.f) ? 1.f : nm;
    }
    __syncthreads();
    for (int c = 0; c < CP1N; c++){
        float ce = ce_s[c];
        if (ce == 0.f) continue;          // uniform across block
        const float* qc = conc + c*DCN;   // wave-uniform address -> scalar loads
        float s = -1e30f;
        if (tid < NNODE){
            float a_ = 0.f;
            const float* gr_ = &gg[tid*65];
            #pragma unroll 16
            for (int d = 0; d < DCN; d++) a_ += qc[d] * gr_[d];
            s = ce * a_;
        }
        float m_ = s;
        #pragma unroll
        for (int m2 = 32; m2; m2 >>= 1) m_ = fmaxf(m_, __shfl_xor(m_, m2));
        if (lane == 0) wredA[wv] = m_;
        __syncthreads();                                    // barrier 1
        float mx = fmaxf(fmaxf(wredA[0], wredA[1]), fmaxf(wredA[2], wredA[3]));
        float e = (tid < NNODE) ? expf(s - mx) : 0.f;
        sc[tid] = e;
        float sum_ = e;
        #pragma unroll
        for (int m2 = 32; m2; m2 >>= 1) sum_ += __shfl_xor(sum_, m2);
        if (lane == 0) wredB[wv] = sum_;
        __syncthreads();                                    // barrier 2
        float inv = ce / (wredB[0]+wredB[1]+wredB[2]+wredB[3]);
        float pa = 0.f;
        for (int n = wv; n < NNODE; n += 4) pa += sc[n] * gg[n*65 + lane];
        part[wv][lane] = pa;
        __syncthreads();                                    // barrier 3
        if (tid < DCN) oacc[tid] += inv * (part[0][tid] + part[1][tid] + part[2][tid] + part[3][tid]);
    }
    __syncthreads();
    if (tid < FEATN){
        float v;
        if      (tid < CP1N)       v = ce_s[tid];
        else if (tid < CP1N+DCN)   v = oacc[tid-CP1N] / num_s;
        else                       v = curres[(size_t)g*2 + (tid-CP1N-DCN)];
        lstm_in[(size_t)g*FEATN + tid] = v;
    }
}

// ---------------------------------------------------------------------------
// gi_all = lstm_in @ Wih^T + (bih + bhh)    (800 x 1024, K=177)
__global__ void __launch_bounds__(256)
k_gi(const float* __restrict__ lstm_in, const float* __restrict__ wihT,
     const float* __restrict__ bih, const float* __restrict__ bhh, float* __restrict__ gi){
    int rb = blockIdx.x;   // 100 blocks of 8 rows
    int jb = blockIdx.y;   // 4
    int tid = threadIdx.x;
    __shared__ float in_s[8][FEATN];
    for (int i = tid; i < 8*FEATN; i += 256){ int r = i/FEATN, k = i%FEATN; in_s[r][k] = lstm_in[((size_t)rb*8+r)*FEATN + k]; }
    __syncthreads();
    int j = jb*256 + tid;
    float acc[8];
    #pragma unroll
    for (int i = 0; i < 8; i++) acc[i] = 0.f;
    for (int k = 0; k < FEATN; k++){
        float w = wihT[(size_t)k*1024 + j];
        #pragma unroll
        for (int i = 0; i < 8; i++) acc[i] += in_s[i][k] * w;
    }
    float b = bih[j] + bhh[j];
    #pragma unroll
    for (int i = 0; i < 8; i++) gi[((size_t)rb*8+i)*1024 + j] = acc[i] + b;
}

// ---------------------------------------------------------------------------
// Sequential LSTM (R7 structure — R8's quad-gate shuffles regressed: ds_bpermute
// on the LDS pipe + 4x transcendental issue). 104 bf16-pairs/thread in VGPRs +
// 24 pairs in LDS as uint4; gates via LDS, 2 barriers/step.
static const int WREG = 104;
static const int WL4  = 6;    // 24 pairs = 6 uint4 groups (pairs 104..127)

__global__ void __launch_bounds__(1024)
__attribute__((amdgpu_waves_per_eu(4,4)))
k_lstm(const float* __restrict__ gi, const unsigned* __restrict__ whhP, float* __restrict__ out){
    int b = blockIdx.x; int tid = threadIdx.x;
    __shared__ uint4 ldsw4[WL4][1024];       // 96 KB
    __shared__ float gates[1024];
    __shared__ __align__(8) u16 h16[HID];    // packed bf16 h, read as u32 pairs
    unsigned wreg[WREG];
    #pragma unroll
    for (int i = 0; i < WREG; i++) wreg[i] = whhP[(size_t)i*1024 + tid];
    #pragma unroll
    for (int q = 0; q < WL4; q++){
        uint4 v;
        v.x = whhP[(size_t)(WREG + 4*q + 0)*1024 + tid];
        v.y = whhP[(size_t)(WREG + 4*q + 1)*1024 + tid];
        v.z = whhP[(size_t)(WREG + 4*q + 2)*1024 + tid];
        v.w = whhP[(size_t)(WREG + 4*q + 3)*1024 + tid];
        ldsw4[q][tid] = v;
    }
    if (tid < 128) ((unsigned*)h16)[tid] = 0u;
    float c_reg = 0.f;
    int lane = tid & 63;
    __syncthreads();
    float giv = gi[(size_t)b*SLN*1024 + tid];
    for (int t = 0; t < SLN; t++){
        unsigned hv0 = ((const unsigned*)h16)[lane];
        unsigned hv1 = ((const unsigned*)h16)[64 + lane];
        float acc0 = giv, acc1 = 0.f;
        if (t+1 < SLN) giv = gi[((size_t)b*SLN + t + 1)*1024 + tid];
        #pragma unroll
        for (int p = 0; p < 64; p += 2){
            unsigned hpa = (unsigned)__builtin_amdgcn_readlane((int)hv0, p);
            unsigned hpb = (unsigned)__builtin_amdgcn_readlane((int)hv0, p+1);
            acc0 = dot2bf(wreg[p],   hpa, acc0);
            acc1 = dot2bf(wreg[p+1], hpb, acc1);
        }
        #pragma unroll
        for (int p = 64; p < WREG; p += 2){
            unsigned hpa = (unsigned)__builtin_amdgcn_readlane((int)hv1, p - 64);
            unsigned hpb = (unsigned)__builtin_amdgcn_readlane((int)hv1, p - 63);
            acc0 = dot2bf(wreg[p],   hpa, acc0);
            acc1 = dot2bf(wreg[p+1], hpb, acc1);
        }
        #pragma unroll
        for (int q = 0; q < WL4; q++){
            uint4 wv = ldsw4[q][tid];
            int base = WREG + 4*q - 64;
            unsigned h0 = (unsigned)__builtin_amdgcn_readlane((int)hv1, base + 0);
            unsigned h1 = (unsigned)__builtin_amdgcn_readlane((int)hv1, base + 1);
            unsigned h2 = (unsigned)__builtin_amdgcn_readlane((int)hv1, base + 2);
            unsigned h3 = (unsigned)__builtin_amdgcn_readlane((int)hv1, base + 3);
            acc0 = dot2bf(wv.x, h0, acc0);
            acc1 = dot2bf(wv.y, h1, acc1);
            acc0 = dot2bf(wv.z, h2, acc0);
            acc1 = dot2bf(wv.w, h3, acc1);
        }
        gates[tid] = acc0 + acc1;
        __syncthreads();
        if (tid < HID){
            float i_ = sigf(gates[tid]);
            float f_ = sigf(gates[tid+256]);
            float g_ = tanhf(gates[tid+512]);
            float o_ = sigf(gates[tid+768]);
            c_reg = f_*c_reg + i_*g_;
            float h = o_*tanhf(c_reg);
            out[((size_t)b*SLN + t)*HID + tid] = h;
            h16[tid] = f2bf(h);
        }
        __syncthreads();
    }
}

// ---------------------------------------------------------------------------
// pred + masked BCE per row; outputs sigmoid(fp), ft; atomics for loss sums.
__global__ void __launch_bounds__(128)
k_final(const float* __restrict__ lstm_out, const float* __restrict__ pw, const float* __restrict__ pb,
        const float* __restrict__ tc, const float* __restrict__ result,
        float* __restrict__ out, float* __restrict__ lacc){
    int row = blockIdx.x; int tid = threadIdx.x;
    __shared__ __align__(16) float h_s[HID];
    __shared__ float redv[128], redn[128];
    h_s[tid]       = lstm_out[(size_t)row*HID + tid];
    h_s[tid + 128] = lstm_out[(size_t)row*HID + tid + 128];
    __syncthreads();
    float v = 0.f, n = 0.f;
    if (tid < CP1N){
        float acc = pb[tid];
        const float4* wr = (const float4*)(pw + (size_t)tid*HID);
        const float4* hp = (const float4*)h_s;
        #pragma unroll 8
        for (int k4 = 0; k4 < 64; k4++){
            float4 w = wr[k4]; float4 h4 = hp[k4];
            acc += h4.x*w.x + h4.y*w.y + h4.z*w.z + h4.w*w.w;
        }
        float t = tc[(size_t)row*CP1N + tid];
        v = acc*t; n = t;
    }
    redv[tid] = v; redn[tid] = n;
    __syncthreads();
    for (int s = 64; s > 0; s >>= 1){
        if (tid < s){ redv[tid] += redv[tid+s]; redn[tid] += redn[tid+s]; }
        __syncthreads();
    }
    if (tid == 0){
        float nc = redn[0];
        bool mask = nc > 0.f;
        float fp = redv[0] / (mask ? nc : 1.f);
        float ft = result[row];
        float bce = fmaxf(fp, 0.f) - fp*ft + log1pf(expf(-fabsf(fp)));
        out[1 + row]      = 1.f/(1.f + expf(-fp));
        out[1 + GN + row] = ft;
        if (mask){ atomicAdd(&lacc[0], bce); atomicAdd(&lacc[1], 1.f); }
    }
}

__global__ void k_loss_final(const float* __restrict__ lacc, float* __restrict__ out){
    out[0] = lacc[0] / fmaxf(lacc[1], 1.f);
}

// ---------------------------------------------------------------------------
extern "C" void kernel_launch(void* const* d_in, const int* in_sizes, int n_in,
                              void* d_out, int out_size, void* d_ws, size_t ws_size,
                              hipStream_t stream) {
    const float* c_id        = (const float*)d_in[1];
    const int*   node_id     = (const int*)  d_in[2];
    const int*   edge        = (const int*)  d_in[3];
    const int*   etype       = (const int*)  d_in[4];
    const float* target_c    = (const float*)d_in[5];
    const float* result      = (const float*)d_in[6];
    const float* c_embed     = (const float*)d_in[7];
    const float* cur_result  = (const float*)d_in[8];
    const float* node_emb_w  = (const float*)d_in[9];
    const float* edge_emb_w  = (const float*)d_in[10];
    const float* ggnn_w      = (const float*)d_in[11];
    const float* gru_w_ih    = (const float*)d_in[12];
    const float* gru_w_hh    = (const float*)d_in[13];
    const float* gru_b_ih    = (const float*)d_in[14];
    const float* gru_b_hh    = (const float*)d_in[15];
    const float* transdim_w  = (const float*)d_in[16];
    const float* concept     = (const float*)d_in[17];
    const float* lstm_w_ih   = (const float*)d_in[18];
    const float* lstm_w_hh   = (const float*)d_in[19];
    const float* lstm_b_ih   = (const float*)d_in[20];
    const float* lstm_b_hh   = (const float*)d_in[21];
    const float* pred_w      = (const float*)d_in[22];
    const float* pred_b      = (const float*)d_in[23];
    float* out = (float*)d_out;

    char* ws = (char*)d_ws;
    size_t off = 0;
    auto alloc = [&](size_t bytes) -> void* {
        void* p = ws + off;
        off += (bytes + 255) & ~(size_t)255;
        return p;
    };
    u16*      xb       = (u16*)     alloc((size_t)MROW*DIM*2);
    u16*      aggb     = (u16*)     alloc((size_t)MROW*DIM*2);
    int*      csr_src  = (int*)     alloc((size_t)GN*NEDGE*4);
    float*    csr_w    = (float*)   alloc((size_t)GN*NEDGE*4);
    int*      csr_off  = (int*)     alloc((size_t)GN*(NNODE+1)*4);
    float*    lstm_in  = (float*)   alloc((size_t)GN*FEATN*4);
    float*    gi       = (float*)   alloc((size_t)GN*1024*4);
    unsigned* whhP     = (unsigned*)alloc((size_t)128*1024*4);
    float*    wihT     = (float*)   alloc((size_t)FEATN*1024*4);
    float*    lstm_out = (float*)   alloc((size_t)GN*HID*4);
    u16*      wihb     = (u16*)     alloc((size_t)384*128*2);
    u16*      whhb     = (u16*)     alloc((size_t)384*128*2);
    u16*      gwTb     = (u16*)     alloc((size_t)4*128*128*2);
    u16*      twb      = (u16*)     alloc((size_t)DCN*DIM*2);
    float*    lacc     = (float*)   alloc(256);
    u16*      ggnn_out = (u16*)aggb;   // aggb dead after layer 4; reuse for bf16 (M x 64)

    hipMemsetAsync(lacc, 0, 8, stream);
    {
        int total = 128*1024 + FEATN*1024;
        k_transpose_w<<<(total + 255)/256, 256, 0, stream>>>(lstm_w_hh, lstm_w_ih, whhP, wihT);
    }
    k_convert_w<<<672, 256, 0, stream>>>(gru_w_ih, gru_w_hh, ggnn_w, transdim_w, wihb, whhb, gwTb, twb);
    k_build_csr<<<GN, 256, 0, stream>>>(edge, etype, edge_emb_w, csr_src, csr_w, csr_off);
    k_gather_x<<<4096, 256, 0, stream>>>(node_id, (const float4*)node_emb_w, (u16x8*)xb);
    for (int l = 0; l < 4; l++){
        k_mm_scatter<<<GN, 256, 0, stream>>>(xb, gwTb + (size_t)l*DIM*DIM,
                                             csr_src, csr_w, csr_off, aggb);
        k_gru_mfma<<<MROW/128, 512, 0, stream>>>(xb, aggb, wihb, whhb, gru_b_ih, gru_b_hh);
    }
    k_transdim<<<MROW/128, 256, 0, stream>>>(xb, twb, ggnn_out);
    k_attention<<<GN, 256, 0, stream>>>(ggnn_out, c_embed, c_id, concept, cur_result, lstm_in);
    k_gi<<<dim3(100, 4), 256, 0, stream>>>(lstm_in, wihT, lstm_b_ih, lstm_b_hh, gi);
    k_lstm<<<BSZ, 1024, 0, stream>>>(gi, whhP, lstm_out);
    k_final<<<GN, 128, 0, stream>>>(lstm_out, pred_w, pred_b, target_c, result, out, lacc);
    k_loss_final<<<1, 1, 0, stream>>>(lacc, out);
}

// Round 10
// 1295.768 us; speedup vs baseline: 1.0518x; 1.0137x over previous
//
#include <hip/hip_runtime.h>
#include <math.h>

// Problem constants
static const int BSZ   = 8;
static const int SLN   = 100;
static const int NNODE = 200;
static const int NEDGE = 600;
static const int CP1N  = 111;
static const int DIM   = 128;
static const int DCN   = 64;
static const int HID   = 256;
static const int FEATN = 177;   // CP1N + DCN + 2
static const int GN    = 800;   // BS*SL
static const int MROW  = 160000; // GN*NNODE

typedef unsigned short u16;
typedef u16    u16x8  __attribute__((ext_vector_type(8)));
typedef __bf16 bf16x8 __attribute__((ext_vector_type(8)));
typedef __bf16 bf16x2 __attribute__((ext_vector_type(2)));
typedef float  f32x16 __attribute__((ext_vector_type(16)));

#if defined(__has_builtin)
# if __has_builtin(__builtin_amdgcn_fdot2_f32_bf16)
#  define HAVE_FDOT2 1
# else
#  define HAVE_FDOT2 0
# endif
# if __has_builtin(__builtin_amdgcn_exp2f)
#  define HAVE_EXP2 1
# else
#  define HAVE_EXP2 0
# endif
# if __has_builtin(__builtin_amdgcn_rcpf)
#  define HAVE_RCP 1
# else
#  define HAVE_RCP 0
# endif
#else
# define HAVE_FDOT2 0
# define HAVE_EXP2 0
# define HAVE_RCP 0
#endif

static __device__ __forceinline__ float fexp2(float x){
#if HAVE_EXP2
    return __builtin_amdgcn_exp2f(x);
#else
    return exp2f(x);
#endif
}
static __device__ __forceinline__ float frcp(float x){
#if HAVE_RCP
    return __builtin_amdgcn_rcpf(x);
#else
    return 1.f/x;
#endif
}
#define LOG2E 1.44269504088896340736f
// fast sigmoid/tanh via v_exp_f32 + v_rcp_f32 (~1e-6 abs err; threshold is 2e-2)
static __device__ __forceinline__ float sigf(float v){ return frcp(1.f + fexp2(-LOG2E*v)); }
static __device__ __forceinline__ float tanh_f(float v){ return 1.f - 2.f*frcp(fexp2(2.f*LOG2E*v) + 1.f); }

__device__ __forceinline__ u16 f2bf(float f){
    union { float f; unsigned u; } v; v.f = f;
    unsigned r = v.u + 0x7FFFu + ((v.u >> 16) & 1u);
    return (u16)(r >> 16);
}
__device__ __forceinline__ float bf2f(u16 u){
    union { unsigned u; float f; } v; v.u = ((unsigned)u) << 16;
    return v.f;
}
__device__ __forceinline__ float dot2bf(unsigned w, unsigned h, float acc){
#if HAVE_FDOT2
    return __builtin_amdgcn_fdot2_f32_bf16(__builtin_bit_cast(bf16x2, w),
                                           __builtin_bit_cast(bf16x2, h), acc, false);
#else
    acc += bf2f((u16)(w & 0xffffu)) * bf2f((u16)(h & 0xffffu));
    acc += bf2f((u16)(w >> 16))     * bf2f((u16)(h >> 16));
    return acc;
#endif
}

// A-fragment LDS slot with XOR bank swizzle (see R9 notes).
__device__ __forceinline__ int afrag_slot(int row, int kc8){
    int kcq = kc8 >> 1;
    int pos = (row & 31) + 32*(kc8 & 1);
    return ((row >> 5)*8 + kcq)*64 + (pos ^ kcq);
}

// ---------------------------------------------------------------------------
// whhP[k2][j] = packed bf16 pair (Whh[j][2k2], Whh[j][2k2+1]);  WihT[k][j] = Wih[j][k] fp32
__global__ void k_transpose_w(const float* __restrict__ whh, const float* __restrict__ wih,
                              unsigned* __restrict__ whhP, float* __restrict__ wihT){
    int idx = blockIdx.x*blockDim.x + threadIdx.x;
    const int total1 = 128*1024;
    if (idx < total1){
        int k2 = idx >> 10, j = idx & 1023;
        u16 lo = f2bf(whh[(size_t)j*256 + 2*k2]);
        u16 hi = f2bf(whh[(size_t)j*256 + 2*k2 + 1]);
        whhP[(size_t)k2*1024 + j] = (unsigned)lo | ((unsigned)hi << 16);
    }
    int idx2 = idx - total1;
    const int total2 = FEATN*1024;
    if (idx2 >= 0 && idx2 < total2){
        int k = idx2 >> 10, j = idx2 & 1023;
        wihT[(size_t)k*1024 + j] = wih[(size_t)j*FEATN + k];
    }
}

// ---------------------------------------------------------------------------
// bf16 weight conversions: wih/whh (GRU, natural layout), gwT (transposed ggnn), tw (natural)
__global__ void k_convert_w(const float* __restrict__ wih, const float* __restrict__ whh,
                            const float* __restrict__ gw, const float* __restrict__ tw,
                            u16* __restrict__ wihb, u16* __restrict__ whhb,
                            u16* __restrict__ gwTb, u16* __restrict__ twb){
    int idx = blockIdx.x*blockDim.x + threadIdx.x;
    if (idx < 49152){
        wihb[idx] = f2bf(wih[idx]);
    } else if (idx < 98304){
        int t = idx - 49152;
        whhb[t] = f2bf(whh[t]);
    } else if (idx < 163840){
        int t = idx - 98304;
        int l = t >> 14, rem = t & 16383, n = rem >> 7, k = rem & 127;
        gwTb[t] = f2bf(gw[((size_t)l*128 + k)*128 + n]);
    } else if (idx < 172032){
        int t = idx - 163840;
        twb[t] = f2bf(tw[t]);
    }
}

// ---------------------------------------------------------------------------
// Per-graph CSR over dst + per-edge weight = mean(edge_embed_w[type])
__global__ void __launch_bounds__(256)
k_build_csr(const int* __restrict__ edge, const int* __restrict__ etype,
            const float* __restrict__ eembed,
            int* __restrict__ csr_src, float* __restrict__ csr_w, int* __restrict__ csr_off){
    int g = blockIdx.x; int tid = threadIdx.x;
    __shared__ float tmean[8];
    __shared__ float tpart[8][32];
    __shared__ int cnt[NNODE];
    __shared__ int offs[NNODE+1];
    __shared__ int cur[NNODE];
    {
        int ty = tid >> 5, lane = tid & 31;
        float s = 0.f;
        for (int i = lane; i < DIM; i += 32) s += eembed[ty*DIM + i];
        tpart[ty][lane] = s;
    }
    for (int i = tid; i < NNODE; i += 256) cnt[i] = 0;
    __syncthreads();
    if (tid < 8){
        float s = 0.f;
        for (int i = 0; i < 32; i++) s += tpart[tid][i];
        tmean[tid] = s / (float)DIM;
    }
    for (int e = tid; e < NEDGE; e += 256){
        int dst = edge[((size_t)g*2+1)*NEDGE + e];
        atomicAdd(&cnt[dst], 1);
    }
    __syncthreads();
    if (tid == 0){
        int run = 0;
        for (int i = 0; i < NNODE; i++){ offs[i] = run; run += cnt[i]; }
        offs[NNODE] = run;
    }
    __syncthreads();
    for (int i = tid; i < NNODE; i += 256) cur[i] = offs[i];
    for (int i = tid; i < NNODE+1; i += 256) csr_off[(size_t)g*(NNODE+1)+i] = offs[i];
    __syncthreads();
    for (int e = tid; e < NEDGE; e += 256){
        int dst = edge[((size_t)g*2+1)*NEDGE + e];
        int src = edge[((size_t)g*2+0)*NEDGE + e];
        float w = tmean[etype[(size_t)g*NEDGE + e]];
        int pos = atomicAdd(&cur[dst], 1);
        csr_src[(size_t)g*NEDGE + pos] = src;
        csr_w [(size_t)g*NEDGE + pos] = w;
    }
}

// ---------------------------------------------------------------------------
// xb = bf16(node_embed_w[node_id])
__global__ void k_gather_x(const int* __restrict__ nid, const float4* __restrict__ emb,
                           u16x8* __restrict__ xb){
    const long total = (long)MROW*16;   // 8-element chunks
    for (long c = (long)blockIdx.x*blockDim.x + threadIdx.x; c < total; c += (long)gridDim.x*blockDim.x){
        long row = c >> 4; int p = (int)(c & 15);
        float4 a = emb[(size_t)nid[row]*32 + p*2];
        float4 b = emb[(size_t)nid[row]*32 + p*2 + 1];
        u16x8 v;
        v[0]=f2bf(a.x); v[1]=f2bf(a.y); v[2]=f2bf(a.z); v[3]=f2bf(a.w);
        v[4]=f2bf(b.x); v[5]=f2bf(b.y); v[6]=f2bf(b.z); v[7]=f2bf(b.w);
        xb[c] = v;
    }
}

// ---------------------------------------------------------------------------
// MFMA m = x_g @ W with A staged coalesced in LDS (swizzled fragment order),
// then m overwrites the SAME LDS buffer, then CSR scatter (2 cols per u32 read).
__global__ void __launch_bounds__(256)
k_mm_scatter(const u16* __restrict__ xb, const u16* __restrict__ gwTb_l,
             const int* __restrict__ csr_src, const float* __restrict__ csr_w,
             const int* __restrict__ csr_off, u16* __restrict__ aggb){
    __shared__ u16 smem[224*128];      // 57344 B: A-frags, later m (bf16)
    __shared__ int   e_src[NEDGE];
    __shared__ float e_w[NEDGE];
    __shared__ int   offs_s[NNODE+1];
    int g = blockIdx.x;
    int tid = threadIdx.x;
    const u16x8* xg = (const u16x8*)(xb + (size_t)g*NNODE*DIM);
    u16x8* afrag = (u16x8*)smem;       // 3584 slots: [tile7][kcq8][pos^kcq]
    for (int c = tid; c < 3584; c += 256){
        int row = c >> 4, kc8 = c & 15;
        u16x8 v = {};
        if (row < NNODE) v = xg[row*16 + kc8];
        afrag[afrag_slot(row, kc8)] = v;
    }
    {
        const int*   srcp = csr_src + (size_t)g*NEDGE;
        const float* wp   = csr_w   + (size_t)g*NEDGE;
        const int*   off  = csr_off + (size_t)g*(NNODE+1);
        for (int i = tid; i < NEDGE; i += 256){ e_src[i] = srcp[i]; e_w[i] = wp[i]; }
        for (int i = tid; i <= NNODE; i += 256) offs_s[i] = off[i];
    }
    __syncthreads();
    int w = tid >> 6, lane = tid & 63;
    int nbase = w*32;
    int m = lane & 31, kh = lane >> 5;
    f32x16 acc[7];
    #pragma unroll
    for (int t = 0; t < 7; t++) acc[t] = (f32x16)0.f;
    const u16x8* bp = (const u16x8*)gwTb_l;
    int nrow = nbase + m;
    #pragma unroll
    for (int kc = 0; kc < 8; kc++){
        u16x8 b = bp[nrow*16 + kc*2 + kh];
        #pragma unroll
        for (int mt = 0; mt < 7; mt++){
            u16x8 a = afrag[(mt*8 + kc)*64 + (lane ^ kc)];
            acc[mt] = __builtin_amdgcn_mfma_f32_32x32x16_bf16(
                __builtin_bit_cast(bf16x8, a), __builtin_bit_cast(bf16x8, b), acc[mt], 0, 0, 0);
        }
    }
    __syncthreads();   // all afrag reads complete before overwrite
    #pragma unroll
    for (int mt = 0; mt < 7; mt++){
        #pragma unroll
        for (int r = 0; r < 16; r++){
            int row = mt*32 + (r&3) + 8*(r>>2) + 4*kh;
            int col = nbase + m;
            smem[row*128 + col] = f2bf(acc[mt][r]);
        }
    }
    __syncthreads();
    const unsigned* m32 = (const unsigned*)smem;
    int j2 = tid & 63, rg = tid >> 6;
    unsigned* aggout = (unsigned*)(aggb + (size_t)g*NNODE*DIM);
    for (int i = 0; i < 50; i++){
        int n = rg*50 + i;
        int b0 = offs_s[n], e0 = offs_s[n+1];
        float a0 = 0.f, a1 = 0.f;
        for (int p = b0; p < e0; p++){
            unsigned mv = m32[e_src[p]*64 + j2];
            float w_ = e_w[p];
            a0 += w_ * bf2f((u16)(mv & 0xffffu));
            a1 += w_ * bf2f((u16)(mv >> 16));
        }
        aggout[(size_t)n*64 + j2] = (unsigned)f2bf(a0) | ((unsigned)f2bf(a1) << 16);
    }
}

// ---------------------------------------------------------------------------
// Fused MFMA GRU layer, M-tile 128. Grid 1250 x 512 threads. Swizzled staging.
__global__ void __launch_bounds__(512, 2)
k_gru_mfma(u16* __restrict__ xb, const u16* __restrict__ aggb,
           const u16* __restrict__ wihb, const u16* __restrict__ whhb,
           const float* __restrict__ bih, const float* __restrict__ bhh){
    __shared__ u16x8 afragA[2048];   // 128 rows: [mtile4][kcq8][pos^kcq]
    __shared__ u16x8 afragX[2048];
    int tid = threadIdx.x;
    long r0 = (long)blockIdx.x * 128;
    const u16x8* aggp = (const u16x8*)aggb;
    const u16x8* xbp  = (const u16x8*)xb;
    for (int c = tid; c < 4096; c += 512){
        int mat = c >> 11, cc = c & 2047;
        int row = cc >> 4, kc8 = cc & 15;
        u16x8 v = (mat ? xbp : aggp)[(r0 + row)*16 + kc8];
        (mat ? afragX : afragA)[afrag_slot(row, kc8)] = v;
    }
    __syncthreads();
    int w = tid >> 6, lane = tid & 63;
    int mtg = w >> 2;              // 0..1 -> rows mtg*64 .. mtg*64+63
    int cb  = (w & 3) * 32;        // col base within 128
    f32x16 acc0[6], acc1[6];
    #pragma unroll
    for (int t = 0; t < 6; t++){ acc0[t] = (f32x16)0.f; acc1[t] = (f32x16)0.f; }
    const u16x8* bi = (const u16x8*)wihb;
    const u16x8* bh = (const u16x8*)whhb;
    int kh = lane >> 5;
    int ncol = cb + (lane & 31);
    #pragma unroll
    for (int kc = 0; kc < 8; kc++){
        int lx = lane ^ kc;
        u16x8 aA0 = afragA[((2*mtg+0)*8 + kc)*64 + lx];
        u16x8 aA1 = afragA[((2*mtg+1)*8 + kc)*64 + lx];
        u16x8 aX0 = afragX[((2*mtg+0)*8 + kc)*64 + lx];
        u16x8 aX1 = afragX[((2*mtg+1)*8 + kc)*64 + lx];
        #pragma unroll
        for (int g3 = 0; g3 < 3; g3++){
            int n = g3*128 + ncol;
            u16x8 b1 = bi[n*16 + kc*2 + kh];
            u16x8 b2 = bh[n*16 + kc*2 + kh];
            acc0[g3]   = __builtin_amdgcn_mfma_f32_32x32x16_bf16(
                __builtin_bit_cast(bf16x8, aA0), __builtin_bit_cast(bf16x8, b1), acc0[g3], 0,0,0);
            acc1[g3]   = __builtin_amdgcn_mfma_f32_32x32x16_bf16(
                __builtin_bit_cast(bf16x8, aA1), __builtin_bit_cast(bf16x8, b1), acc1[g3], 0,0,0);
            acc0[3+g3] = __builtin_amdgcn_mfma_f32_32x32x16_bf16(
                __builtin_bit_cast(bf16x8, aX0), __builtin_bit_cast(bf16x8, b2), acc0[3+g3], 0,0,0);
            acc1[3+g3] = __builtin_amdgcn_mfma_f32_32x32x16_bf16(
                __builtin_bit_cast(bf16x8, aX1), __builtin_bit_cast(bf16x8, b2), acc1[3+g3], 0,0,0);
        }
    }
    int col = cb + (lane & 31);
    float bir = bih[col], biz = bih[col+128], bin = bih[col+256];
    float bhr = bhh[col], bhz = bhh[col+128], bhn = bhh[col+256];
    int kc8c = col >> 3, elc = col & 7;
    #pragma unroll
    for (int mt2 = 0; mt2 < 2; mt2++){
        const f32x16* ac = mt2 ? acc1 : acc0;
        #pragma unroll
        for (int r = 0; r < 16; r++){
            int row = mtg*64 + mt2*32 + (r&3) + 8*(r>>2) + 4*kh;
            u16x8 xv = afragX[afrag_slot(row, kc8c)];
            float xo = bf2f(((const u16*)&xv)[elc]);
            float rr  = sigf(ac[0][r] + bir + ac[3][r] + bhr);
            float zz  = sigf(ac[1][r] + biz + ac[4][r] + bhz);
            float nn_ = tanh_f(ac[2][r] + bin + rr*(ac[5][r] + bhn));
            float xn  = (1.f - zz)*nn_ + zz*xo;
            xb[(size_t)(r0 + row)*DIM + col] = f2bf(xn);
        }
    }
}

// ---------------------------------------------------------------------------
// FUSED transdim + attention. One block (256 thr) per graph.
// Phase 1: stage x-frags (57 KB swizzled), MFMA gg = x @ tw^T (224x64).
// Phase 2: write gg fp32 into the SAME LDS buffer (accs live in registers
// across the barrier), then the attention loop runs from LDS. Saves the
// 40 MB gout HBM round-trip + one dispatch.
__global__ void __launch_bounds__(256)
k_attention(const u16* __restrict__ xb, const u16* __restrict__ twb,
            const float* __restrict__ cemb, const float* __restrict__ cid,
            const float* __restrict__ conc, const float* __restrict__ curres,
            float* __restrict__ lstm_in){
    int g = blockIdx.x; int tid = threadIdx.x;
    int lane = tid & 63, wv = tid >> 6;
    __shared__ __align__(16) unsigned char smem_raw[57344];  // x-frags, later gg
    __shared__ float ce_s[CP1N];
    __shared__ float sc[256];
    __shared__ float wredA[4];
    __shared__ float wredB[4];
    __shared__ float part[4][DCN];
    __shared__ float oacc[DCN];
    __shared__ float num_s;
    u16x8* afrag = (u16x8*)smem_raw;
    float* gg    = (float*)smem_raw;     // 200*65*4 = 52000 B <= 57344
    const u16x8* xg = (const u16x8*)(xb + (size_t)g*NNODE*DIM);
    for (int c = tid; c < 3584; c += 256){
        int row = c >> 4, kc8 = c & 15;
        u16x8 v = {};
        if (row < NNODE) v = xg[row*16 + kc8];
        afrag[afrag_slot(row, kc8)] = v;
    }
    if (tid < CP1N) ce_s[tid] = cemb[(size_t)g*CP1N + tid];
    if (tid < DCN) oacc[tid] = 0.f;
    {
        float v = (tid < CP1N) ? cid[(size_t)g*CP1N + tid] : 0.f;
        #pragma unroll
        for (int m2 = 32; m2; m2 >>= 1) v += __shfl_xor(v, m2);
        if (lane == 0) wredA[wv] = v;
    }
    __syncthreads();
    if (tid == 0){
        float nm = wredA[0]+wredA[1]+wredA[2]+wredA[3];
        num_s = (nm == 0.f) ? 1.f : nm;
    }
    // MFMA: wave wv: col-tile ct = wv&1, row-tiles tb..tb+nt-1 (tb = (wv>>1)?4:0)
    {
        int ct = wv & 1, rh = wv >> 1;
        int tb = rh ? 4 : 0, nt = rh ? 3 : 4;
        int m = lane & 31, kh = lane >> 5;
        f32x16 acc[4];
        #pragma unroll
        for (int t = 0; t < 4; t++) acc[t] = (f32x16)0.f;
        const u16x8* tp = (const u16x8*)twb;
        #pragma unroll
        for (int kc = 0; kc < 8; kc++){
            u16x8 b = tp[(ct*32 + m)*16 + kc*2 + kh];
            for (int t = 0; t < nt; t++){
                u16x8 a = afrag[((tb+t)*8 + kc)*64 + (lane ^ kc)];
                acc[t] = __builtin_amdgcn_mfma_f32_32x32x16_bf16(
                    __builtin_bit_cast(bf16x8, a), __builtin_bit_cast(bf16x8, b), acc[t], 0,0,0);
            }
        }
        __syncthreads();   // all afrag reads done before gg overwrite
        for (int t = 0; t < nt; t++){
            #pragma unroll
            for (int r = 0; r < 16; r++){
                int row = (tb+t)*32 + (r&3) + 8*(r>>2) + 4*kh;
                int col = ct*32 + m;
                if (row < NNODE) gg[row*65 + col] = acc[t][r];
            }
        }
    }
    __syncthreads();
    // Attention loop (from LDS gg)
    for (int c = 0; c < CP1N; c++){
        float ce = ce_s[c];
        if (ce == 0.f) continue;          // uniform across block
        const float* qc = conc + c*DCN;   // wave-uniform address -> scalar loads
        float s = -1e30f;
        if (tid < NNODE){
            float a_ = 0.f;
            const float* gr_ = &gg[tid*65];
            #pragma unroll 16
            for (int d = 0; d < DCN; d++) a_ += qc[d] * gr_[d];
            s = ce * a_;
        }
        float m_ = s;
        #pragma unroll
        for (int m2 = 32; m2; m2 >>= 1) m_ = fmaxf(m_, __shfl_xor(m_, m2));
        if (lane == 0) wredA[wv] = m_;
        __syncthreads();                                    // barrier 1
        float mx = fmaxf(fmaxf(wredA[0], wredA[1]), fmaxf(wredA[2], wredA[3]));
        float e = (tid < NNODE) ? fexp2(LOG2E*(s - mx)) : 0.f;
        sc[tid] = e;
        float sum_ = e;
        #pragma unroll
        for (int m2 = 32; m2; m2 >>= 1) sum_ += __shfl_xor(sum_, m2);
        if (lane == 0) wredB[wv] = sum_;
        __syncthreads();                                    // barrier 2
        float inv = ce / (wredB[0]+wredB[1]+wredB[2]+wredB[3]);
        float pa = 0.f;
        for (int n = wv; n < NNODE; n += 4) pa += sc[n] * gg[n*65 + lane];
        part[wv][lane] = pa;
        __syncthreads();                                    // barrier 3
        if (tid < DCN) oacc[tid] += inv * (part[0][tid] + part[1][tid] + part[2][tid] + part[3][tid]);
    }
    __syncthreads();
    if (tid < FEATN){
        float v;
        if      (tid < CP1N)       v = ce_s[tid];
        else if (tid < CP1N+DCN)   v = oacc[tid-CP1N] / num_s;
        else                       v = curres[(size_t)g*2 + (tid-CP1N-DCN)];
        lstm_in[(size_t)g*FEATN + tid] = v;
    }
}

// ---------------------------------------------------------------------------
// gi_all = lstm_in @ Wih^T + (bih + bhh)    (800 x 1024, K=177)
__global__ void __launch_bounds__(256)
k_gi(const float* __restrict__ lstm_in, const float* __restrict__ wihT,
     const float* __restrict__ bih, const float* __restrict__ bhh, float* __restrict__ gi){
    int rb = blockIdx.x;   // 100 blocks of 8 rows
    int jb = blockIdx.y;   // 4
    int tid = threadIdx.x;
    __shared__ float in_s[8][FEATN];
    for (int i = tid; i < 8*FEATN; i += 256){ int r = i/FEATN, k = i%FEATN; in_s[r][k] = lstm_in[((size_t)rb*8+r)*FEATN + k]; }
    __syncthreads();
    int j = jb*256 + tid;
    float acc[8];
    #pragma unroll
    for (int i = 0; i < 8; i++) acc[i] = 0.f;
    for (int k = 0; k < FEATN; k++){
        float w = wihT[(size_t)k*1024 + j];
        #pragma unroll
        for (int i = 0; i < 8; i++) acc[i] += in_s[i][k] * w;
    }
    float b = bih[j] + bhh[j];
    #pragma unroll
    for (int i = 0; i < 8; i++) gi[((size_t)rb*8+i)*1024 + j] = acc[i] + b;
}

// ---------------------------------------------------------------------------
// Sequential LSTM (R7 structure). 104 bf16-pairs/thread in VGPRs + 24 pairs in
// LDS as uint4; gates via LDS, 2 barriers/step.
static const int WREG = 104;
static const int WL4  = 6;    // 24 pairs = 6 uint4 groups (pairs 104..127)

__global__ void __launch_bounds__(1024)
__attribute__((amdgpu_waves_per_eu(4,4)))
k_lstm(const float* __restrict__ gi, const unsigned* __restrict__ whhP, float* __restrict__ out){
    int b = blockIdx.x; int tid = threadIdx.x;
    __shared__ uint4 ldsw4[WL4][1024];       // 96 KB
    __shared__ float gates[1024];
    __shared__ __align__(8) u16 h16[HID];    // packed bf16 h, read as u32 pairs
    unsigned wreg[WREG];
    #pragma unroll
    for (int i = 0; i < WREG; i++) wreg[i] = whhP[(size_t)i*1024 + tid];
    #pragma unroll
    for (int q = 0; q < WL4; q++){
        uint4 v;
        v.x = whhP[(size_t)(WREG + 4*q + 0)*1024 + tid];
        v.y = whhP[(size_t)(WREG + 4*q + 1)*1024 + tid];
        v.z = whhP[(size_t)(WREG + 4*q + 2)*1024 + tid];
        v.w = whhP[(size_t)(WREG + 4*q + 3)*1024 + tid];
        ldsw4[q][tid] = v;
    }
    if (tid < 128) ((unsigned*)h16)[tid] = 0u;
    float c_reg = 0.f;
    int lane = tid & 63;
    __syncthreads();
    float giv = gi[(size_t)b*SLN*1024 + tid];
    for (int t = 0; t < SLN; t++){
        unsigned hv0 = ((const unsigned*)h16)[lane];
        unsigned hv1 = ((const unsigned*)h16)[64 + lane];
        float acc0 = giv, acc1 = 0.f;
        if (t+1 < SLN) giv = gi[((size_t)b*SLN + t + 1)*1024 + tid];
        #pragma unroll
        for (int p = 0; p < 64; p += 2){
            unsigned hpa = (unsigned)__builtin_amdgcn_readlane((int)hv0, p);
            unsigned hpb = (unsigned)__builtin_amdgcn_readlane((int)hv0, p+1);
            acc0 = dot2bf(wreg[p],   hpa, acc0);
            acc1 = dot2bf(wreg[p+1], hpb, acc1);
        }
        #pragma unroll
        for (int p = 64; p < WREG; p += 2){
            unsigned hpa = (unsigned)__builtin_amdgcn_readlane((int)hv1, p - 64);
            unsigned hpb = (unsigned)__builtin_amdgcn_readlane((int)hv1, p - 63);
            acc0 = dot2bf(wreg[p],   hpa, acc0);
            acc1 = dot2bf(wreg[p+1], hpb, acc1);
        }
        #pragma unroll
        for (int q = 0; q < WL4; q++){
            uint4 wv = ldsw4[q][tid];
            int base = WREG + 4*q - 64;
            unsigned h0 = (unsigned)__builtin_amdgcn_readlane((int)hv1, base + 0);
            unsigned h1 = (unsigned)__builtin_amdgcn_readlane((int)hv1, base + 1);
            unsigned h2 = (unsigned)__builtin_amdgcn_readlane((int)hv1, base + 2);
            unsigned h3 = (unsigned)__builtin_amdgcn_readlane((int)hv1, base + 3);
            acc0 = dot2bf(wv.x, h0, acc0);
            acc1 = dot2bf(wv.y, h1, acc1);
            acc0 = dot2bf(wv.z, h2, acc0);
            acc1 = dot2bf(wv.w, h3, acc1);
        }
        gates[tid] = acc0 + acc1;
        __syncthreads();
        if (tid < HID){
            float i_ = sigf(gates[tid]);
            float f_ = sigf(gates[tid+256]);
            float g_ = tanh_f(gates[tid+512]);
            float o_ = sigf(gates[tid+768]);
            c_reg = f_*c_reg + i_*g_;
            float h = o_*tanh_f(c_reg);
            out[((size_t)b*SLN + t)*HID + tid] = h;
            h16[tid] = f2bf(h);
        }
        __syncthreads();
    }
}

// ---------------------------------------------------------------------------
// pred + masked BCE per row; outputs sigmoid(fp), ft; atomics for loss sums.
// (kept precise libm — 800 rows, negligible cost, touches outputs directly)
__global__ void __launch_bounds__(128)
k_final(const float* __restrict__ lstm_out, const float* __restrict__ pw, const float* __restrict__ pb,
        const float* __restrict__ tc, const float* __restrict__ result,
        float* __restrict__ out, float* __restrict__ lacc){
    int row = blockIdx.x; int tid = threadIdx.x;
    __shared__ __align__(16) float h_s[HID];
    __shared__ float redv[128], redn[128];
    h_s[tid]       = lstm_out[(size_t)row*HID + tid];
    h_s[tid + 128] = lstm_out[(size_t)row*HID + tid + 128];
    __syncthreads();
    float v = 0.f, n = 0.f;
    if (tid < CP1N){
        float acc = pb[tid];
        const float4* wr = (const float4*)(pw + (size_t)tid*HID);
        const float4* hp = (const float4*)h_s;
        #pragma unroll 8
        for (int k4 = 0; k4 < 64; k4++){
            float4 w = wr[k4]; float4 h4 = hp[k4];
            acc += h4.x*w.x + h4.y*w.y + h4.z*w.z + h4.w*w.w;
        }
        float t = tc[(size_t)row*CP1N + tid];
        v = acc*t; n = t;
    }
    redv[tid] = v; redn[tid] = n;
    __syncthreads();
    for (int s = 64; s > 0; s >>= 1){
        if (tid < s){ redv[tid] += redv[tid+s]; redn[tid] += redn[tid+s]; }
        __syncthreads();
    }
    if (tid == 0){
        float nc = redn[0];
        bool mask = nc > 0.f;
        float fp = redv[0] / (mask ? nc : 1.f);
        float ft = result[row];
        float bce = fmaxf(fp, 0.f) - fp*ft + log1pf(expf(-fabsf(fp)));
        out[1 + row]      = 1.f/(1.f + expf(-fp));
        out[1 + GN + row] = ft;
        if (mask){ atomicAdd(&lacc[0], bce); atomicAdd(&lacc[1], 1.f); }
    }
}

__global__ void k_loss_final(const float* __restrict__ lacc, float* __restrict__ out){
    out[0] = lacc[0] / fmaxf(lacc[1], 1.f);
}

// ---------------------------------------------------------------------------
extern "C" void kernel_launch(void* const* d_in, const int* in_sizes, int n_in,
                              void* d_out, int out_size, void* d_ws, size_t ws_size,
                              hipStream_t stream) {
    const float* c_id        = (const float*)d_in[1];
    const int*   node_id     = (const int*)  d_in[2];
    const int*   edge        = (const int*)  d_in[3];
    const int*   etype       = (const int*)  d_in[4];
    const float* target_c    = (const float*)d_in[5];
    const float* result      = (const float*)d_in[6];
    const float* c_embed     = (const float*)d_in[7];
    const float* cur_result  = (const float*)d_in[8];
    const float* node_emb_w  = (const float*)d_in[9];
    const float* edge_emb_w  = (const float*)d_in[10];
    const float* ggnn_w      = (const float*)d_in[11];
    const float* gru_w_ih    = (const float*)d_in[12];
    const float* gru_w_hh    = (const float*)d_in[13];
    const float* gru_b_ih    = (const float*)d_in[14];
    const float* gru_b_hh    = (const float*)d_in[15];
    const float* transdim_w  = (const float*)d_in[16];
    const float* concept     = (const float*)d_in[17];
    const float* lstm_w_ih   = (const float*)d_in[18];
    const float* lstm_w_hh   = (const float*)d_in[19];
    const float* lstm_b_ih   = (const float*)d_in[20];
    const float* lstm_b_hh   = (const float*)d_in[21];
    const float* pred_w      = (const float*)d_in[22];
    const float* pred_b      = (const float*)d_in[23];
    float* out = (float*)d_out;

    char* ws = (char*)d_ws;
    size_t off = 0;
    auto alloc = [&](size_t bytes) -> void* {
        void* p = ws + off;
        off += (bytes + 255) & ~(size_t)255;
        return p;
    };
    u16*      xb       = (u16*)     alloc((size_t)MROW*DIM*2);
    u16*      aggb     = (u16*)     alloc((size_t)MROW*DIM*2);
    int*      csr_src  = (int*)     alloc((size_t)GN*NEDGE*4);
    float*    csr_w    = (float*)   alloc((size_t)GN*NEDGE*4);
    int*      csr_off  = (int*)     alloc((size_t)GN*(NNODE+1)*4);
    float*    lstm_in  = (float*)   alloc((size_t)GN*FEATN*4);
    float*    gi       = (float*)   alloc((size_t)GN*1024*4);
    unsigned* whhP     = (unsigned*)alloc((size_t)128*1024*4);
    float*    wihT     = (float*)   alloc((size_t)FEATN*1024*4);
    float*    lstm_out = (float*)   alloc((size_t)GN*HID*4);
    u16*      wihb     = (u16*)     alloc((size_t)384*128*2);
    u16*      whhb     = (u16*)     alloc((size_t)384*128*2);
    u16*      gwTb     = (u16*)     alloc((size_t)4*128*128*2);
    u16*      twb      = (u16*)     alloc((size_t)DCN*DIM*2);
    float*    lacc     = (float*)   alloc(256);

    hipMemsetAsync(lacc, 0, 8, stream);
    {
        int total = 128*1024 + FEATN*1024;
        k_transpose_w<<<(total + 255)/256, 256, 0, stream>>>(lstm_w_hh, lstm_w_ih, whhP, wihT);
    }
    k_convert_w<<<672, 256, 0, stream>>>(gru_w_ih, gru_w_hh, ggnn_w, transdim_w, wihb, whhb, gwTb, twb);
    k_build_csr<<<GN, 256, 0, stream>>>(edge, etype, edge_emb_w, csr_src, csr_w, csr_off);
    k_gather_x<<<4096, 256, 0, stream>>>(node_id, (const float4*)node_emb_w, (u16x8*)xb);
    for (int l = 0; l < 4; l++){
        k_mm_scatter<<<GN, 256, 0, stream>>>(xb, gwTb + (size_t)l*DIM*DIM,
                                             csr_src, csr_w, csr_off, aggb);
        k_gru_mfma<<<MROW/128, 512, 0, stream>>>(xb, aggb, wihb, whhb, gru_b_ih, gru_b_hh);
    }
    k_attention<<<GN, 256, 0, stream>>>(xb, twb, c_embed, c_id, concept, cur_result, lstm_in);
    k_gi<<<dim3(100, 4), 256, 0, stream>>>(lstm_in, wihT, lstm_b_ih, lstm_b_hh, gi);
    k_lstm<<<BSZ, 1024, 0, stream>>>(gi, whhP, lstm_out);
    k_final<<<GN, 128, 0, stream>>>(lstm_out, pred_w, pred_b, target_c, result, out, lacc);
    k_loss_final<<<1, 1, 0, stream>>>(lacc, out);
}

// Round 11
// 1188.818 us; speedup vs baseline: 1.1464x; 1.0900x over previous
//
#include <hip/hip_runtime.h>
#include <math.h>

// Problem constants
static const int BSZ   = 8;
static const int SLN   = 100;
static const int NNODE = 200;
static const int NEDGE = 600;
static const int CP1N  = 111;
static const int DIM   = 128;
static const int DCN   = 64;
static const int HID   = 256;
static const int FEATN = 177;   // CP1N + DCN + 2
static const int GN    = 800;   // BS*SL
static const int MROW  = 160000; // GN*NNODE

typedef unsigned short u16;
typedef u16    u16x8  __attribute__((ext_vector_type(8)));
typedef __bf16 bf16x8 __attribute__((ext_vector_type(8)));
typedef __bf16 bf16x2 __attribute__((ext_vector_type(2)));
typedef float  f32x16 __attribute__((ext_vector_type(16)));

#if defined(__has_builtin)
# if __has_builtin(__builtin_amdgcn_fdot2_f32_bf16)
#  define HAVE_FDOT2 1
# else
#  define HAVE_FDOT2 0
# endif
# if __has_builtin(__builtin_amdgcn_exp2f)
#  define HAVE_EXP2 1
# else
#  define HAVE_EXP2 0
# endif
# if __has_builtin(__builtin_amdgcn_rcpf)
#  define HAVE_RCP 1
# else
#  define HAVE_RCP 0
# endif
#else
# define HAVE_FDOT2 0
# define HAVE_EXP2 0
# define HAVE_RCP 0
#endif

static __device__ __forceinline__ float fexp2(float x){
#if HAVE_EXP2
    return __builtin_amdgcn_exp2f(x);
#else
    return exp2f(x);
#endif
}
static __device__ __forceinline__ float frcp(float x){
#if HAVE_RCP
    return __builtin_amdgcn_rcpf(x);
#else
    return 1.f/x;
#endif
}
#define LOG2E 1.44269504088896340736f
// fast sigmoid/tanh via v_exp_f32 + v_rcp_f32 (~1e-6 abs err; threshold is 2e-2)
static __device__ __forceinline__ float sigf(float v){ return frcp(1.f + fexp2(-LOG2E*v)); }
static __device__ __forceinline__ float tanh_f(float v){ return 1.f - 2.f*frcp(fexp2(2.f*LOG2E*v) + 1.f); }

__device__ __forceinline__ u16 f2bf(float f){
    union { float f; unsigned u; } v; v.f = f;
    unsigned r = v.u + 0x7FFFu + ((v.u >> 16) & 1u);
    return (u16)(r >> 16);
}
__device__ __forceinline__ float bf2f(u16 u){
    union { unsigned u; float f; } v; v.u = ((unsigned)u) << 16;
    return v.f;
}
__device__ __forceinline__ float dot2bf(unsigned w, unsigned h, float acc){
#if HAVE_FDOT2
    return __builtin_amdgcn_fdot2_f32_bf16(__builtin_bit_cast(bf16x2, w),
                                           __builtin_bit_cast(bf16x2, h), acc, false);
#else
    acc += bf2f((u16)(w & 0xffffu)) * bf2f((u16)(h & 0xffffu));
    acc += bf2f((u16)(w >> 16))     * bf2f((u16)(h >> 16));
    return acc;
#endif
}

// A-fragment LDS slot with XOR bank swizzle (see R9 notes).
__device__ __forceinline__ int afrag_slot(int row, int kc8){
    int kcq = kc8 >> 1;
    int pos = (row & 31) + 32*(kc8 & 1);
    return ((row >> 5)*8 + kcq)*64 + (pos ^ kcq);
}

// ---------------------------------------------------------------------------
// whhP[k2][j] = packed bf16 pair (Whh[j][2k2], Whh[j][2k2+1]);  WihT[k][j] = Wih[j][k] fp32
__global__ void k_transpose_w(const float* __restrict__ whh, const float* __restrict__ wih,
                              unsigned* __restrict__ whhP, float* __restrict__ wihT){
    int idx = blockIdx.x*blockDim.x + threadIdx.x;
    const int total1 = 128*1024;
    if (idx < total1){
        int k2 = idx >> 10, j = idx & 1023;
        u16 lo = f2bf(whh[(size_t)j*256 + 2*k2]);
        u16 hi = f2bf(whh[(size_t)j*256 + 2*k2 + 1]);
        whhP[(size_t)k2*1024 + j] = (unsigned)lo | ((unsigned)hi << 16);
    }
    int idx2 = idx - total1;
    const int total2 = FEATN*1024;
    if (idx2 >= 0 && idx2 < total2){
        int k = idx2 >> 10, j = idx2 & 1023;
        wihT[(size_t)k*1024 + j] = wih[(size_t)j*FEATN + k];
    }
}

// ---------------------------------------------------------------------------
// bf16 weight conversions: wih/whh (GRU, natural layout), gwT (transposed ggnn), tw (natural)
__global__ void k_convert_w(const float* __restrict__ wih, const float* __restrict__ whh,
                            const float* __restrict__ gw, const float* __restrict__ tw,
                            u16* __restrict__ wihb, u16* __restrict__ whhb,
                            u16* __restrict__ gwTb, u16* __restrict__ twb){
    int idx = blockIdx.x*blockDim.x + threadIdx.x;
    if (idx < 49152){
        wihb[idx] = f2bf(wih[idx]);
    } else if (idx < 98304){
        int t = idx - 49152;
        whhb[t] = f2bf(whh[t]);
    } else if (idx < 163840){
        int t = idx - 98304;
        int l = t >> 14, rem = t & 16383, n = rem >> 7, k = rem & 127;
        gwTb[t] = f2bf(gw[((size_t)l*128 + k)*128 + n]);
    } else if (idx < 172032){
        int t = idx - 163840;
        twb[t] = f2bf(tw[t]);
    }
}

// ---------------------------------------------------------------------------
// Per-graph CSR over dst + per-edge weight = mean(edge_embed_w[type])
__global__ void __launch_bounds__(256)
k_build_csr(const int* __restrict__ edge, const int* __restrict__ etype,
            const float* __restrict__ eembed,
            int* __restrict__ csr_src, float* __restrict__ csr_w, int* __restrict__ csr_off){
    int g = blockIdx.x; int tid = threadIdx.x;
    __shared__ float tmean[8];
    __shared__ float tpart[8][32];
    __shared__ int cnt[NNODE];
    __shared__ int offs[NNODE+1];
    __shared__ int cur[NNODE];
    {
        int ty = tid >> 5, lane = tid & 31;
        float s = 0.f;
        for (int i = lane; i < DIM; i += 32) s += eembed[ty*DIM + i];
        tpart[ty][lane] = s;
    }
    for (int i = tid; i < NNODE; i += 256) cnt[i] = 0;
    __syncthreads();
    if (tid < 8){
        float s = 0.f;
        for (int i = 0; i < 32; i++) s += tpart[tid][i];
        tmean[tid] = s / (float)DIM;
    }
    for (int e = tid; e < NEDGE; e += 256){
        int dst = edge[((size_t)g*2+1)*NEDGE + e];
        atomicAdd(&cnt[dst], 1);
    }
    __syncthreads();
    if (tid == 0){
        int run = 0;
        for (int i = 0; i < NNODE; i++){ offs[i] = run; run += cnt[i]; }
        offs[NNODE] = run;
    }
    __syncthreads();
    for (int i = tid; i < NNODE; i += 256) cur[i] = offs[i];
    for (int i = tid; i < NNODE+1; i += 256) csr_off[(size_t)g*(NNODE+1)+i] = offs[i];
    __syncthreads();
    for (int e = tid; e < NEDGE; e += 256){
        int dst = edge[((size_t)g*2+1)*NEDGE + e];
        int src = edge[((size_t)g*2+0)*NEDGE + e];
        float w = tmean[etype[(size_t)g*NEDGE + e]];
        int pos = atomicAdd(&cur[dst], 1);
        csr_src[(size_t)g*NEDGE + pos] = src;
        csr_w [(size_t)g*NEDGE + pos] = w;
    }
}

// ---------------------------------------------------------------------------
// xb = bf16(node_embed_w[node_id])
__global__ void k_gather_x(const int* __restrict__ nid, const float4* __restrict__ emb,
                           u16x8* __restrict__ xb){
    const long total = (long)MROW*16;   // 8-element chunks
    for (long c = (long)blockIdx.x*blockDim.x + threadIdx.x; c < total; c += (long)gridDim.x*blockDim.x){
        long row = c >> 4; int p = (int)(c & 15);
        float4 a = emb[(size_t)nid[row]*32 + p*2];
        float4 b = emb[(size_t)nid[row]*32 + p*2 + 1];
        u16x8 v;
        v[0]=f2bf(a.x); v[1]=f2bf(a.y); v[2]=f2bf(a.z); v[3]=f2bf(a.w);
        v[4]=f2bf(b.x); v[5]=f2bf(b.y); v[6]=f2bf(b.z); v[7]=f2bf(b.w);
        xb[c] = v;
    }
}

// ---------------------------------------------------------------------------
// MFMA m = x_g @ W with A staged coalesced in LDS (swizzled fragment order),
// then m overwrites the SAME LDS buffer, then CSR scatter (2 cols per u32 read).
__global__ void __launch_bounds__(256)
k_mm_scatter(const u16* __restrict__ xb, const u16* __restrict__ gwTb_l,
             const int* __restrict__ csr_src, const float* __restrict__ csr_w,
             const int* __restrict__ csr_off, u16* __restrict__ aggb){
    __shared__ u16 smem[224*128];      // 57344 B: A-frags, later m (bf16)
    __shared__ int   e_src[NEDGE];
    __shared__ float e_w[NEDGE];
    __shared__ int   offs_s[NNODE+1];
    int g = blockIdx.x;
    int tid = threadIdx.x;
    const u16x8* xg = (const u16x8*)(xb + (size_t)g*NNODE*DIM);
    u16x8* afrag = (u16x8*)smem;       // 3584 slots: [tile7][kcq8][pos^kcq]
    for (int c = tid; c < 3584; c += 256){
        int row = c >> 4, kc8 = c & 15;
        u16x8 v = {};
        if (row < NNODE) v = xg[row*16 + kc8];
        afrag[afrag_slot(row, kc8)] = v;
    }
    {
        const int*   srcp = csr_src + (size_t)g*NEDGE;
        const float* wp   = csr_w   + (size_t)g*NEDGE;
        const int*   off  = csr_off + (size_t)g*(NNODE+1);
        for (int i = tid; i < NEDGE; i += 256){ e_src[i] = srcp[i]; e_w[i] = wp[i]; }
        for (int i = tid; i <= NNODE; i += 256) offs_s[i] = off[i];
    }
    __syncthreads();
    int w = tid >> 6, lane = tid & 63;
    int nbase = w*32;
    int m = lane & 31, kh = lane >> 5;
    f32x16 acc[7];
    #pragma unroll
    for (int t = 0; t < 7; t++) acc[t] = (f32x16)0.f;
    const u16x8* bp = (const u16x8*)gwTb_l;
    int nrow = nbase + m;
    #pragma unroll
    for (int kc = 0; kc < 8; kc++){
        u16x8 b = bp[nrow*16 + kc*2 + kh];
        #pragma unroll
        for (int mt = 0; mt < 7; mt++){
            u16x8 a = afrag[(mt*8 + kc)*64 + (lane ^ kc)];
            acc[mt] = __builtin_amdgcn_mfma_f32_32x32x16_bf16(
                __builtin_bit_cast(bf16x8, a), __builtin_bit_cast(bf16x8, b), acc[mt], 0, 0, 0);
        }
    }
    __syncthreads();   // all afrag reads complete before overwrite
    #pragma unroll
    for (int mt = 0; mt < 7; mt++){
        #pragma unroll
        for (int r = 0; r < 16; r++){
            int row = mt*32 + (r&3) + 8*(r>>2) + 4*kh;
            int col = nbase + m;
            smem[row*128 + col] = f2bf(acc[mt][r]);
        }
    }
    __syncthreads();
    const unsigned* m32 = (const unsigned*)smem;
    int j2 = tid & 63, rg = tid >> 6;
    unsigned* aggout = (unsigned*)(aggb + (size_t)g*NNODE*DIM);
    for (int i = 0; i < 50; i++){
        int n = rg*50 + i;
        int b0 = offs_s[n], e0 = offs_s[n+1];
        float a0 = 0.f, a1 = 0.f;
        for (int p = b0; p < e0; p++){
            unsigned mv = m32[e_src[p]*64 + j2];
            float w_ = e_w[p];
            a0 += w_ * bf2f((u16)(mv & 0xffffu));
            a1 += w_ * bf2f((u16)(mv >> 16));
        }
        aggout[(size_t)n*64 + j2] = (unsigned)f2bf(a0) | ((unsigned)f2bf(a1) << 16);
    }
}

// ---------------------------------------------------------------------------
// Fused MFMA GRU layer, M-tile 128. Grid 1250 x 512 threads. Swizzled staging.
__global__ void __launch_bounds__(512, 2)
k_gru_mfma(u16* __restrict__ xb, const u16* __restrict__ aggb,
           const u16* __restrict__ wihb, const u16* __restrict__ whhb,
           const float* __restrict__ bih, const float* __restrict__ bhh){
    __shared__ u16x8 afragA[2048];   // 128 rows: [mtile4][kcq8][pos^kcq]
    __shared__ u16x8 afragX[2048];
    int tid = threadIdx.x;
    long r0 = (long)blockIdx.x * 128;
    const u16x8* aggp = (const u16x8*)aggb;
    const u16x8* xbp  = (const u16x8*)xb;
    for (int c = tid; c < 4096; c += 512){
        int mat = c >> 11, cc = c & 2047;
        int row = cc >> 4, kc8 = cc & 15;
        u16x8 v = (mat ? xbp : aggp)[(r0 + row)*16 + kc8];
        (mat ? afragX : afragA)[afrag_slot(row, kc8)] = v;
    }
    __syncthreads();
    int w = tid >> 6, lane = tid & 63;
    int mtg = w >> 2;              // 0..1 -> rows mtg*64 .. mtg*64+63
    int cb  = (w & 3) * 32;        // col base within 128
    f32x16 acc0[6], acc1[6];
    #pragma unroll
    for (int t = 0; t < 6; t++){ acc0[t] = (f32x16)0.f; acc1[t] = (f32x16)0.f; }
    const u16x8* bi = (const u16x8*)wihb;
    const u16x8* bh = (const u16x8*)whhb;
    int kh = lane >> 5;
    int ncol = cb + (lane & 31);
    #pragma unroll
    for (int kc = 0; kc < 8; kc++){
        int lx = lane ^ kc;
        u16x8 aA0 = afragA[((2*mtg+0)*8 + kc)*64 + lx];
        u16x8 aA1 = afragA[((2*mtg+1)*8 + kc)*64 + lx];
        u16x8 aX0 = afragX[((2*mtg+0)*8 + kc)*64 + lx];
        u16x8 aX1 = afragX[((2*mtg+1)*8 + kc)*64 + lx];
        #pragma unroll
        for (int g3 = 0; g3 < 3; g3++){
            int n = g3*128 + ncol;
            u16x8 b1 = bi[n*16 + kc*2 + kh];
            u16x8 b2 = bh[n*16 + kc*2 + kh];
            acc0[g3]   = __builtin_amdgcn_mfma_f32_32x32x16_bf16(
                __builtin_bit_cast(bf16x8, aA0), __builtin_bit_cast(bf16x8, b1), acc0[g3], 0,0,0);
            acc1[g3]   = __builtin_amdgcn_mfma_f32_32x32x16_bf16(
                __builtin_bit_cast(bf16x8, aA1), __builtin_bit_cast(bf16x8, b1), acc1[g3], 0,0,0);
            acc0[3+g3] = __builtin_amdgcn_mfma_f32_32x32x16_bf16(
                __builtin_bit_cast(bf16x8, aX0), __builtin_bit_cast(bf16x8, b2), acc0[3+g3], 0,0,0);
            acc1[3+g3] = __builtin_amdgcn_mfma_f32_32x32x16_bf16(
                __builtin_bit_cast(bf16x8, aX1), __builtin_bit_cast(bf16x8, b2), acc1[3+g3], 0,0,0);
        }
    }
    int col = cb + (lane & 31);
    float bir = bih[col], biz = bih[col+128], bin = bih[col+256];
    float bhr = bhh[col], bhz = bhh[col+128], bhn = bhh[col+256];
    int kc8c = col >> 3, elc = col & 7;
    #pragma unroll
    for (int mt2 = 0; mt2 < 2; mt2++){
        const f32x16* ac = mt2 ? acc1 : acc0;
        #pragma unroll
        for (int r = 0; r < 16; r++){
            int row = mtg*64 + mt2*32 + (r&3) + 8*(r>>2) + 4*kh;
            u16x8 xv = afragX[afrag_slot(row, kc8c)];
            float xo = bf2f(((const u16*)&xv)[elc]);
            float rr  = sigf(ac[0][r] + bir + ac[3][r] + bhr);
            float zz  = sigf(ac[1][r] + biz + ac[4][r] + bhz);
            float nn_ = tanh_f(ac[2][r] + bin + rr*(ac[5][r] + bhn));
            float xn  = (1.f - zz)*nn_ + zz*xo;
            xb[(size_t)(r0 + row)*DIM + col] = f2bf(xn);
        }
    }
}

// ---------------------------------------------------------------------------
// FUSED transdim + attention. One block (256 thr) per graph.
// Phase 1: stage x-frags (57 KB swizzled), MFMA gg = x @ tw^T.
// Phase 2: gg fp32 overwrites the same LDS; attention loop from LDS.
// R10 BUG FIXED: the tile loop is now compile-time unrolled with a
// wave-uniform guard (t < ntile) so acc[] stays in VGPRs. R10's runtime
// loop bound demoted acc[] to scratch -> 225 MB of HBM scratch traffic,
// 255 us for this kernel.
__global__ void __launch_bounds__(256)
k_attention(const u16* __restrict__ xb, const u16* __restrict__ twb,
            const float* __restrict__ cemb, const float* __restrict__ cid,
            const float* __restrict__ conc, const float* __restrict__ curres,
            float* __restrict__ lstm_in){
    int g = blockIdx.x; int tid = threadIdx.x;
    int lane = tid & 63, wv = tid >> 6;
    __shared__ __align__(16) unsigned char smem_raw[57344];  // x-frags, later gg
    __shared__ float ce_s[CP1N];
    __shared__ float sc[256];
    __shared__ float wredA[4];
    __shared__ float wredB[4];
    __shared__ float part[4][DCN];
    __shared__ float oacc[DCN];
    __shared__ float num_s;
    u16x8* afrag = (u16x8*)smem_raw;
    float* gg    = (float*)smem_raw;     // 200*65*4 = 52000 B <= 57344
    const u16x8* xg = (const u16x8*)(xb + (size_t)g*NNODE*DIM);
    for (int c = tid; c < 3584; c += 256){
        int row = c >> 4, kc8 = c & 15;
        u16x8 v = {};
        if (row < NNODE) v = xg[row*16 + kc8];
        afrag[afrag_slot(row, kc8)] = v;
    }
    if (tid < CP1N) ce_s[tid] = cemb[(size_t)g*CP1N + tid];
    if (tid < DCN) oacc[tid] = 0.f;
    {
        float v = (tid < CP1N) ? cid[(size_t)g*CP1N + tid] : 0.f;
        #pragma unroll
        for (int m2 = 32; m2; m2 >>= 1) v += __shfl_xor(v, m2);
        if (lane == 0) wredA[wv] = v;
    }
    __syncthreads();
    if (tid == 0){
        float nm = wredA[0]+wredA[1]+wredA[2]+wredA[3];
        num_s = (nm == 0.f) ? 1.f : nm;
    }
    // MFMA phase: wave wv -> col-tile ct = wv&1; row-tiles tb..tb+ntile-1
    {
        int ct = wv & 1, rh = wv >> 1;
        int tb = rh ? 4 : 0;
        int ntile = rh ? 3 : 4;          // wave-uniform
        int m = lane & 31, kh = lane >> 5;
        f32x16 acc[4];
        #pragma unroll
        for (int t = 0; t < 4; t++) acc[t] = (f32x16)0.f;
        const u16x8* tp = (const u16x8*)twb;
        #pragma unroll
        for (int kc = 0; kc < 8; kc++){
            u16x8 b = tp[(ct*32 + m)*16 + kc*2 + kh];
            #pragma unroll
            for (int t = 0; t < 4; t++){
                if (t < ntile){          // compile-time t, uniform guard -> regs
                    u16x8 a = afrag[((tb+t)*8 + kc)*64 + (lane ^ kc)];
                    acc[t] = __builtin_amdgcn_mfma_f32_32x32x16_bf16(
                        __builtin_bit_cast(bf16x8, a), __builtin_bit_cast(bf16x8, b), acc[t], 0,0,0);
                }
            }
        }
        __syncthreads();   // all afrag reads done before gg overwrite
        #pragma unroll
        for (int t = 0; t < 4; t++){
            if (t < ntile){
                #pragma unroll
                for (int r = 0; r < 16; r++){
                    int row = (tb+t)*32 + (r&3) + 8*(r>>2) + 4*kh;
                    int col = ct*32 + m;
                    if (row < NNODE) gg[row*65 + col] = acc[t][r];
                }
            }
        }
    }
    __syncthreads();
    // Attention loop (from LDS gg)
    for (int c = 0; c < CP1N; c++){
        float ce = ce_s[c];
        if (ce == 0.f) continue;          // uniform across block
        const float* qc = conc + c*DCN;   // wave-uniform address -> scalar loads
        float s = -1e30f;
        if (tid < NNODE){
            float a_ = 0.f;
            const float* gr_ = &gg[tid*65];
            #pragma unroll 16
            for (int d = 0; d < DCN; d++) a_ += qc[d] * gr_[d];
            s = ce * a_;
        }
        float m_ = s;
        #pragma unroll
        for (int m2 = 32; m2; m2 >>= 1) m_ = fmaxf(m_, __shfl_xor(m_, m2));
        if (lane == 0) wredA[wv] = m_;
        __syncthreads();                                    // barrier 1
        float mx = fmaxf(fmaxf(wredA[0], wredA[1]), fmaxf(wredA[2], wredA[3]));
        float e = (tid < NNODE) ? fexp2(LOG2E*(s - mx)) : 0.f;
        sc[tid] = e;
        float sum_ = e;
        #pragma unroll
        for (int m2 = 32; m2; m2 >>= 1) sum_ += __shfl_xor(sum_, m2);
        if (lane == 0) wredB[wv] = sum_;
        __syncthreads();                                    // barrier 2
        float inv = ce / (wredB[0]+wredB[1]+wredB[2]+wredB[3]);
        float pa = 0.f;
        for (int n = wv; n < NNODE; n += 4) pa += sc[n] * gg[n*65 + lane];
        part[wv][lane] = pa;
        __syncthreads();                                    // barrier 3
        if (tid < DCN) oacc[tid] += inv * (part[0][tid] + part[1][tid] + part[2][tid] + part[3][tid]);
    }
    __syncthreads();
    if (tid < FEATN){
        float v;
        if      (tid < CP1N)       v = ce_s[tid];
        else if (tid < CP1N+DCN)   v = oacc[tid-CP1N] / num_s;
        else                       v = curres[(size_t)g*2 + (tid-CP1N-DCN)];
        lstm_in[(size_t)g*FEATN + tid] = v;
    }
}

// ---------------------------------------------------------------------------
// gi_all = lstm_in @ Wih^T + (bih + bhh)    (800 x 1024, K=177)
__global__ void __launch_bounds__(256)
k_gi(const float* __restrict__ lstm_in, const float* __restrict__ wihT,
     const float* __restrict__ bih, const float* __restrict__ bhh, float* __restrict__ gi){
    int rb = blockIdx.x;   // 100 blocks of 8 rows
    int jb = blockIdx.y;   // 4
    int tid = threadIdx.x;
    __shared__ float in_s[8][FEATN];
    for (int i = tid; i < 8*FEATN; i += 256){ int r = i/FEATN, k = i%FEATN; in_s[r][k] = lstm_in[((size_t)rb*8+r)*FEATN + k]; }
    __syncthreads();
    int j = jb*256 + tid;
    float acc[8];
    #pragma unroll
    for (int i = 0; i < 8; i++) acc[i] = 0.f;
    for (int k = 0; k < FEATN; k++){
        float w = wihT[(size_t)k*1024 + j];
        #pragma unroll
        for (int i = 0; i < 8; i++) acc[i] += in_s[i][k] * w;
    }
    float b = bih[j] + bhh[j];
    #pragma unroll
    for (int i = 0; i < 8; i++) gi[((size_t)rb*8+i)*1024 + j] = acc[i] + b;
}

// ---------------------------------------------------------------------------
// Sequential LSTM (R7 structure). 104 bf16-pairs/thread in VGPRs + 24 pairs in
// LDS as uint4; gates via LDS, 2 barriers/step.
static const int WREG = 104;
static const int WL4  = 6;    // 24 pairs = 6 uint4 groups (pairs 104..127)

__global__ void __launch_bounds__(1024)
__attribute__((amdgpu_waves_per_eu(4,4)))
k_lstm(const float* __restrict__ gi, const unsigned* __restrict__ whhP, float* __restrict__ out){
    int b = blockIdx.x; int tid = threadIdx.x;
    __shared__ uint4 ldsw4[WL4][1024];       // 96 KB
    __shared__ float gates[1024];
    __shared__ __align__(8) u16 h16[HID];    // packed bf16 h, read as u32 pairs
    unsigned wreg[WREG];
    #pragma unroll
    for (int i = 0; i < WREG; i++) wreg[i] = whhP[(size_t)i*1024 + tid];
    #pragma unroll
    for (int q = 0; q < WL4; q++){
        uint4 v;
        v.x = whhP[(size_t)(WREG + 4*q + 0)*1024 + tid];
        v.y = whhP[(size_t)(WREG + 4*q + 1)*1024 + tid];
        v.z = whhP[(size_t)(WREG + 4*q + 2)*1024 + tid];
        v.w = whhP[(size_t)(WREG + 4*q + 3)*1024 + tid];
        ldsw4[q][tid] = v;
    }
    if (tid < 128) ((unsigned*)h16)[tid] = 0u;
    float c_reg = 0.f;
    int lane = tid & 63;
    __syncthreads();
    float giv = gi[(size_t)b*SLN*1024 + tid];
    for (int t = 0; t < SLN; t++){
        unsigned hv0 = ((const unsigned*)h16)[lane];
        unsigned hv1 = ((const unsigned*)h16)[64 + lane];
        float acc0 = giv, acc1 = 0.f;
        if (t+1 < SLN) giv = gi[((size_t)b*SLN + t + 1)*1024 + tid];
        #pragma unroll
        for (int p = 0; p < 64; p += 2){
            unsigned hpa = (unsigned)__builtin_amdgcn_readlane((int)hv0, p);
            unsigned hpb = (unsigned)__builtin_amdgcn_readlane((int)hv0, p+1);
            acc0 = dot2bf(wreg[p],   hpa, acc0);
            acc1 = dot2bf(wreg[p+1], hpb, acc1);
        }
        #pragma unroll
        for (int p = 64; p < WREG; p += 2){
            unsigned hpa = (unsigned)__builtin_amdgcn_readlane((int)hv1, p - 64);
            unsigned hpb = (unsigned)__builtin_amdgcn_readlane((int)hv1, p - 63);
            acc0 = dot2bf(wreg[p],   hpa, acc0);
            acc1 = dot2bf(wreg[p+1], hpb, acc1);
        }
        #pragma unroll
        for (int q = 0; q < WL4; q++){
            uint4 wv = ldsw4[q][tid];
            int base = WREG + 4*q - 64;
            unsigned h0 = (unsigned)__builtin_amdgcn_readlane((int)hv1, base + 0);
            unsigned h1 = (unsigned)__builtin_amdgcn_readlane((int)hv1, base + 1);
            unsigned h2 = (unsigned)__builtin_amdgcn_readlane((int)hv1, base + 2);
            unsigned h3 = (unsigned)__builtin_amdgcn_readlane((int)hv1, base + 3);
            acc0 = dot2bf(wv.x, h0, acc0);
            acc1 = dot2bf(wv.y, h1, acc1);
            acc0 = dot2bf(wv.z, h2, acc0);
            acc1 = dot2bf(wv.w, h3, acc1);
        }
        gates[tid] = acc0 + acc1;
        __syncthreads();
        if (tid < HID){
            float i_ = sigf(gates[tid]);
            float f_ = sigf(gates[tid+256]);
            float g_ = tanh_f(gates[tid+512]);
            float o_ = sigf(gates[tid+768]);
            c_reg = f_*c_reg + i_*g_;
            float h = o_*tanh_f(c_reg);
            out[((size_t)b*SLN + t)*HID + tid] = h;
            h16[tid] = f2bf(h);
        }
        __syncthreads();
    }
}

// ---------------------------------------------------------------------------
// pred + masked BCE per row; outputs sigmoid(fp), ft; atomics for loss sums.
__global__ void __launch_bounds__(128)
k_final(const float* __restrict__ lstm_out, const float* __restrict__ pw, const float* __restrict__ pb,
        const float* __restrict__ tc, const float* __restrict__ result,
        float* __restrict__ out, float* __restrict__ lacc){
    int row = blockIdx.x; int tid = threadIdx.x;
    __shared__ __align__(16) float h_s[HID];
    __shared__ float redv[128], redn[128];
    h_s[tid]       = lstm_out[(size_t)row*HID + tid];
    h_s[tid + 128] = lstm_out[(size_t)row*HID + tid + 128];
    __syncthreads();
    float v = 0.f, n = 0.f;
    if (tid < CP1N){
        float acc = pb[tid];
        const float4* wr = (const float4*)(pw + (size_t)tid*HID);
        const float4* hp = (const float4*)h_s;
        #pragma unroll 8
        for (int k4 = 0; k4 < 64; k4++){
            float4 w = wr[k4]; float4 h4 = hp[k4];
            acc += h4.x*w.x + h4.y*w.y + h4.z*w.z + h4.w*w.w;
        }
        float t = tc[(size_t)row*CP1N + tid];
        v = acc*t; n = t;
    }
    redv[tid] = v; redn[tid] = n;
    __syncthreads();
    for (int s = 64; s > 0; s >>= 1){
        if (tid < s){ redv[tid] += redv[tid+s]; redn[tid] += redn[tid+s]; }
        __syncthreads();
    }
    if (tid == 0){
        float nc = redn[0];
        bool mask = nc > 0.f;
        float fp = redv[0] / (mask ? nc : 1.f);
        float ft = result[row];
        float bce = fmaxf(fp, 0.f) - fp*ft + log1pf(expf(-fabsf(fp)));
        out[1 + row]      = 1.f/(1.f + expf(-fp));
        out[1 + GN + row] = ft;
        if (mask){ atomicAdd(&lacc[0], bce); atomicAdd(&lacc[1], 1.f); }
    }
}

__global__ void k_loss_final(const float* __restrict__ lacc, float* __restrict__ out){
    out[0] = lacc[0] / fmaxf(lacc[1], 1.f);
}

// ---------------------------------------------------------------------------
extern "C" void kernel_launch(void* const* d_in, const int* in_sizes, int n_in,
                              void* d_out, int out_size, void* d_ws, size_t ws_size,
                              hipStream_t stream) {
    const float* c_id        = (const float*)d_in[1];
    const int*   node_id     = (const int*)  d_in[2];
    const int*   edge        = (const int*)  d_in[3];
    const int*   etype       = (const int*)  d_in[4];
    const float* target_c    = (const float*)d_in[5];
    const float* result      = (const float*)d_in[6];
    const float* c_embed     = (const float*)d_in[7];
    const float* cur_result  = (const float*)d_in[8];
    const float* node_emb_w  = (const float*)d_in[9];
    const float* edge_emb_w  = (const float*)d_in[10];
    const float* ggnn_w      = (const float*)d_in[11];
    const float* gru_w_ih    = (const float*)d_in[12];
    const float* gru_w_hh    = (const float*)d_in[13];
    const float* gru_b_ih    = (const float*)d_in[14];
    const float* gru_b_hh    = (const float*)d_in[15];
    const float* transdim_w  = (const float*)d_in[16];
    const float* concept     = (const float*)d_in[17];
    const float* lstm_w_ih   = (const float*)d_in[18];
    const float* lstm_w_hh   = (const float*)d_in[19];
    const float* lstm_b_ih   = (const float*)d_in[20];
    const float* lstm_b_hh   = (const float*)d_in[21];
    const float* pred_w      = (const float*)d_in[22];
    const float* pred_b      = (const float*)d_in[23];
    float* out = (float*)d_out;

    char* ws = (char*)d_ws;
    size_t off = 0;
    auto alloc = [&](size_t bytes) -> void* {
        void* p = ws + off;
        off += (bytes + 255) & ~(size_t)255;
        return p;
    };
    u16*      xb       = (u16*)     alloc((size_t)MROW*DIM*2);
    u16*      aggb     = (u16*)     alloc((size_t)MROW*DIM*2);
    int*      csr_src  = (int*)     alloc((size_t)GN*NEDGE*4);
    float*    csr_w    = (float*)   alloc((size_t)GN*NEDGE*4);
    int*      csr_off  = (int*)     alloc((size_t)GN*(NNODE+1)*4);
    float*    lstm_in  = (float*)   alloc((size_t)GN*FEATN*4);
    float*    gi       = (float*)   alloc((size_t)GN*1024*4);
    unsigned* whhP     = (unsigned*)alloc((size_t)128*1024*4);
    float*    wihT     = (float*)   alloc((size_t)FEATN*1024*4);
    float*    lstm_out = (float*)   alloc((size_t)GN*HID*4);
    u16*      wihb     = (u16*)     alloc((size_t)384*128*2);
    u16*      whhb     = (u16*)     alloc((size_t)384*128*2);
    u16*      gwTb     = (u16*)     alloc((size_t)4*128*128*2);
    u16*      twb      = (u16*)     alloc((size_t)DCN*DIM*2);
    float*    lacc     = (float*)   alloc(256);

    hipMemsetAsync(lacc, 0, 8, stream);
    {
        int total = 128*1024 + FEATN*1024;
        k_transpose_w<<<(total + 255)/256, 256, 0, stream>>>(lstm_w_hh, lstm_w_ih, whhP, wihT);
    }
    k_convert_w<<<672, 256, 0, stream>>>(gru_w_ih, gru_w_hh, ggnn_w, transdim_w, wihb, whhb, gwTb, twb);
    k_build_csr<<<GN, 256, 0, stream>>>(edge, etype, edge_emb_w, csr_src, csr_w, csr_off);
    k_gather_x<<<4096, 256, 0, stream>>>(node_id, (const float4*)node_emb_w, (u16x8*)xb);
    for (int l = 0; l < 4; l++){
        k_mm_scatter<<<GN, 256, 0, stream>>>(xb, gwTb + (size_t)l*DIM*DIM,
                                             csr_src, csr_w, csr_off, aggb);
        k_gru_mfma<<<MROW/128, 512, 0, stream>>>(xb, aggb, wihb, whhb, gru_b_ih, gru_b_hh);
    }
    k_attention<<<GN, 256, 0, stream>>>(xb, twb, c_embed, c_id, concept, cur_result, lstm_in);
    k_gi<<<dim3(100, 4), 256, 0, stream>>>(lstm_in, wihT, lstm_b_ih, lstm_b_hh, gi);
    k_lstm<<<BSZ, 1024, 0, stream>>>(gi, whhP, lstm_out);
    k_final<<<GN, 128, 0, stream>>>(lstm_out, pred_w, pred_b, target_c, result, out, lacc);
    k_loss_final<<<1, 1, 0, stream>>>(lacc, out);
}

// Round 12
// 1120.558 us; speedup vs baseline: 1.2162x; 1.0609x over previous
//
#include <hip/hip_runtime.h>
#include <math.h>

// Problem constants
static const int BSZ   = 8;
static const int SLN   = 100;
static const int NNODE = 200;
static const int NEDGE = 600;
static const int CP1N  = 111;
static const int DIM   = 128;
static const int DCN   = 64;
static const int HID   = 256;
static const int FEATN = 177;   // CP1N + DCN + 2
static const int GN    = 800;   // BS*SL
static const int MROW  = 160000; // GN*NNODE

typedef unsigned short u16;
typedef u16    u16x8  __attribute__((ext_vector_type(8)));
typedef __bf16 bf16x8 __attribute__((ext_vector_type(8)));
typedef __bf16 bf16x2 __attribute__((ext_vector_type(2)));
typedef float  f32x16 __attribute__((ext_vector_type(16)));

#if defined(__has_builtin)
# if __has_builtin(__builtin_amdgcn_fdot2_f32_bf16)
#  define HAVE_FDOT2 1
# else
#  define HAVE_FDOT2 0
# endif
# if __has_builtin(__builtin_amdgcn_exp2f)
#  define HAVE_EXP2 1
# else
#  define HAVE_EXP2 0
# endif
# if __has_builtin(__builtin_amdgcn_rcpf)
#  define HAVE_RCP 1
# else
#  define HAVE_RCP 0
# endif
#else
# define HAVE_FDOT2 0
# define HAVE_EXP2 0
# define HAVE_RCP 0
#endif

static __device__ __forceinline__ float fexp2(float x){
#if HAVE_EXP2
    return __builtin_amdgcn_exp2f(x);
#else
    return exp2f(x);
#endif
}
static __device__ __forceinline__ float frcp(float x){
#if HAVE_RCP
    return __builtin_amdgcn_rcpf(x);
#else
    return 1.f/x;
#endif
}
#define LOG2E 1.44269504088896340736f
static __device__ __forceinline__ float sigf(float v){ return frcp(1.f + fexp2(-LOG2E*v)); }
static __device__ __forceinline__ float tanh_f(float v){ return 1.f - 2.f*frcp(fexp2(2.f*LOG2E*v) + 1.f); }

__device__ __forceinline__ u16 f2bf(float f){
    union { float f; unsigned u; } v; v.f = f;
    unsigned r = v.u + 0x7FFFu + ((v.u >> 16) & 1u);
    return (u16)(r >> 16);
}
__device__ __forceinline__ float bf2f(u16 u){
    union { unsigned u; float f; } v; v.u = ((unsigned)u) << 16;
    return v.f;
}
__device__ __forceinline__ float dot2bf(unsigned w, unsigned h, float acc){
#if HAVE_FDOT2
    return __builtin_amdgcn_fdot2_f32_bf16(__builtin_bit_cast(bf16x2, w),
                                           __builtin_bit_cast(bf16x2, h), acc, false);
#else
    acc += bf2f((u16)(w & 0xffffu)) * bf2f((u16)(h & 0xffffu));
    acc += bf2f((u16)(w >> 16))     * bf2f((u16)(h >> 16));
    return acc;
#endif
}

// A-fragment LDS slot with XOR bank swizzle (see R9 notes).
__device__ __forceinline__ int afrag_slot(int row, int kc8){
    int kcq = kc8 >> 1;
    int pos = (row & 31) + 32*(kc8 & 1);
    return ((row >> 5)*8 + kcq)*64 + (pos ^ kcq);
}

__device__ __forceinline__ u16x8 pack_emb(const float4* __restrict__ emb, int id, int kc8){
    float4 a = emb[(size_t)id*32 + kc8*2];
    float4 b = emb[(size_t)id*32 + kc8*2 + 1];
    u16x8 v;
    v[0]=f2bf(a.x); v[1]=f2bf(a.y); v[2]=f2bf(a.z); v[3]=f2bf(a.w);
    v[4]=f2bf(b.x); v[5]=f2bf(b.y); v[6]=f2bf(b.z); v[7]=f2bf(b.w);
    return v;
}

// ---------------------------------------------------------------------------
// whhP[k2][j] = packed bf16 pair (Whh[j][2k2], Whh[j][2k2+1]);  WihT[k][j] = Wih[j][k] fp32
__global__ void k_transpose_w(const float* __restrict__ whh, const float* __restrict__ wih,
                              unsigned* __restrict__ whhP, float* __restrict__ wihT){
    int idx = blockIdx.x*blockDim.x + threadIdx.x;
    const int total1 = 128*1024;
    if (idx < total1){
        int k2 = idx >> 10, j = idx & 1023;
        u16 lo = f2bf(whh[(size_t)j*256 + 2*k2]);
        u16 hi = f2bf(whh[(size_t)j*256 + 2*k2 + 1]);
        whhP[(size_t)k2*1024 + j] = (unsigned)lo | ((unsigned)hi << 16);
    }
    int idx2 = idx - total1;
    const int total2 = FEATN*1024;
    if (idx2 >= 0 && idx2 < total2){
        int k = idx2 >> 10, j = idx2 & 1023;
        wihT[(size_t)k*1024 + j] = wih[(size_t)j*FEATN + k];
    }
}

// ---------------------------------------------------------------------------
// bf16 weight conversions
__global__ void k_convert_w(const float* __restrict__ wih, const float* __restrict__ whh,
                            const float* __restrict__ gw, const float* __restrict__ tw,
                            u16* __restrict__ wihb, u16* __restrict__ whhb,
                            u16* __restrict__ gwTb, u16* __restrict__ twb){
    int idx = blockIdx.x*blockDim.x + threadIdx.x;
    if (idx < 49152){
        wihb[idx] = f2bf(wih[idx]);
    } else if (idx < 98304){
        int t = idx - 49152;
        whhb[t] = f2bf(whh[t]);
    } else if (idx < 163840){
        int t = idx - 98304;
        int l = t >> 14, rem = t & 16383, n = rem >> 7, k = rem & 127;
        gwTb[t] = f2bf(gw[((size_t)l*128 + k)*128 + n]);
    } else if (idx < 172032){
        int t = idx - 163840;
        twb[t] = f2bf(tw[t]);
    }
}

// ---------------------------------------------------------------------------
// Per-graph CSR over dst + per-edge weight = mean(edge_embed_w[type])
__global__ void __launch_bounds__(256)
k_build_csr(const int* __restrict__ edge, const int* __restrict__ etype,
            const float* __restrict__ eembed,
            int* __restrict__ csr_src, float* __restrict__ csr_w, int* __restrict__ csr_off){
    int g = blockIdx.x; int tid = threadIdx.x;
    __shared__ float tmean[8];
    __shared__ float tpart[8][32];
    __shared__ int cnt[NNODE];
    __shared__ int offs[NNODE+1];
    __shared__ int cur[NNODE];
    {
        int ty = tid >> 5, lane = tid & 31;
        float s = 0.f;
        for (int i = lane; i < DIM; i += 32) s += eembed[ty*DIM + i];
        tpart[ty][lane] = s;
    }
    for (int i = tid; i < NNODE; i += 256) cnt[i] = 0;
    __syncthreads();
    if (tid < 8){
        float s = 0.f;
        for (int i = 0; i < 32; i++) s += tpart[tid][i];
        tmean[tid] = s / (float)DIM;
    }
    for (int e = tid; e < NEDGE; e += 256){
        int dst = edge[((size_t)g*2+1)*NEDGE + e];
        atomicAdd(&cnt[dst], 1);
    }
    __syncthreads();
    if (tid == 0){
        int run = 0;
        for (int i = 0; i < NNODE; i++){ offs[i] = run; run += cnt[i]; }
        offs[NNODE] = run;
    }
    __syncthreads();
    for (int i = tid; i < NNODE; i += 256) cur[i] = offs[i];
    for (int i = tid; i < NNODE+1; i += 256) csr_off[(size_t)g*(NNODE+1)+i] = offs[i];
    __syncthreads();
    for (int e = tid; e < NEDGE; e += 256){
        int dst = edge[((size_t)g*2+1)*NEDGE + e];
        int src = edge[((size_t)g*2+0)*NEDGE + e];
        float w = tmean[etype[(size_t)g*NEDGE + e]];
        int pos = atomicAdd(&cur[dst], 1);
        csr_src[(size_t)g*NEDGE + pos] = src;
        csr_w [(size_t)g*NEDGE + pos] = w;
    }
}

// ---------------------------------------------------------------------------
// MFMA m = x_g @ W (A staged from xb, or gathered from emb when first=1),
// m overwrites the same LDS, then CSR scatter (2 cols per u32 read).
__global__ void __launch_bounds__(256)
k_mm_scatter(const u16* __restrict__ xb, const u16* __restrict__ gwTb_l,
             const int* __restrict__ csr_src, const float* __restrict__ csr_w,
             const int* __restrict__ csr_off, u16* __restrict__ aggb,
             const float4* __restrict__ emb, const int* __restrict__ nid, int first){
    __shared__ u16 smem[224*128];      // 57344 B: A-frags, later m (bf16)
    __shared__ int   e_src[NEDGE];
    __shared__ float e_w[NEDGE];
    __shared__ int   offs_s[NNODE+1];
    int g = blockIdx.x;
    int tid = threadIdx.x;
    u16x8* afrag = (u16x8*)smem;       // 3584 slots: [tile7][kcq8][pos^kcq]
    if (first){
        for (int c = tid; c < 3584; c += 256){
            int row = c >> 4, kc8 = c & 15;
            u16x8 v = {};
            if (row < NNODE) v = pack_emb(emb, nid[(size_t)g*NNODE + row], kc8);
            afrag[afrag_slot(row, kc8)] = v;
        }
    } else {
        const u16x8* xg = (const u16x8*)(xb + (size_t)g*NNODE*DIM);
        for (int c = tid; c < 3584; c += 256){
            int row = c >> 4, kc8 = c & 15;
            u16x8 v = {};
            if (row < NNODE) v = xg[row*16 + kc8];
            afrag[afrag_slot(row, kc8)] = v;
        }
    }
    {
        const int*   srcp = csr_src + (size_t)g*NEDGE;
        const float* wp   = csr_w   + (size_t)g*NEDGE;
        const int*   off  = csr_off + (size_t)g*(NNODE+1);
        for (int i = tid; i < NEDGE; i += 256){ e_src[i] = srcp[i]; e_w[i] = wp[i]; }
        for (int i = tid; i <= NNODE; i += 256) offs_s[i] = off[i];
    }
    __syncthreads();
    int w = tid >> 6, lane = tid & 63;
    int nbase = w*32;
    int m = lane & 31, kh = lane >> 5;
    f32x16 acc[7];
    #pragma unroll
    for (int t = 0; t < 7; t++) acc[t] = (f32x16)0.f;
    const u16x8* bp = (const u16x8*)gwTb_l;
    int nrow = nbase + m;
    #pragma unroll
    for (int kc = 0; kc < 8; kc++){
        u16x8 b = bp[nrow*16 + kc*2 + kh];
        #pragma unroll
        for (int mt = 0; mt < 7; mt++){
            u16x8 a = afrag[(mt*8 + kc)*64 + (lane ^ kc)];
            acc[mt] = __builtin_amdgcn_mfma_f32_32x32x16_bf16(
                __builtin_bit_cast(bf16x8, a), __builtin_bit_cast(bf16x8, b), acc[mt], 0, 0, 0);
        }
    }
    __syncthreads();   // all afrag reads complete before overwrite
    #pragma unroll
    for (int mt = 0; mt < 7; mt++){
        #pragma unroll
        for (int r = 0; r < 16; r++){
            int row = mt*32 + (r&3) + 8*(r>>2) + 4*kh;
            int col = nbase + m;
            smem[row*128 + col] = f2bf(acc[mt][r]);
        }
    }
    __syncthreads();
    const unsigned* m32 = (const unsigned*)smem;
    int j2 = tid & 63, rg = tid >> 6;
    unsigned* aggout = (unsigned*)(aggb + (size_t)g*NNODE*DIM);
    for (int i = 0; i < 50; i++){
        int n = rg*50 + i;
        int b0 = offs_s[n], e0 = offs_s[n+1];
        float a0 = 0.f, a1 = 0.f;
        for (int p = b0; p < e0; p++){
            unsigned mv = m32[e_src[p]*64 + j2];
            float w_ = e_w[p];
            a0 += w_ * bf2f((u16)(mv & 0xffffu));
            a1 += w_ * bf2f((u16)(mv >> 16));
        }
        aggout[(size_t)n*64 + j2] = (unsigned)f2bf(a0) | ((unsigned)f2bf(a1) << 16);
    }
}

// ---------------------------------------------------------------------------
// Fused MFMA GRU layer, M-tile 128. Grid 1250 x 512 threads. Swizzled staging.
// first=1: x staged by gathering emb[nid[...]] (layer 0; xb not yet written).
__global__ void __launch_bounds__(512, 2)
k_gru_mfma(u16* __restrict__ xb, const u16* __restrict__ aggb,
           const u16* __restrict__ wihb, const u16* __restrict__ whhb,
           const float* __restrict__ bih, const float* __restrict__ bhh,
           const float4* __restrict__ emb, const int* __restrict__ nid, int first){
    __shared__ u16x8 afragA[2048];   // 128 rows: [mtile4][kcq8][pos^kcq]
    __shared__ u16x8 afragX[2048];
    int tid = threadIdx.x;
    long r0 = (long)blockIdx.x * 128;
    const u16x8* aggp = (const u16x8*)aggb;
    if (first){
        for (int c = tid; c < 2048; c += 512){
            int row = c >> 4, kc8 = c & 15;
            afragX[afrag_slot(row, kc8)] = pack_emb(emb, nid[r0 + row], kc8);
        }
        for (int c = tid; c < 2048; c += 512){
            int row = c >> 4, kc8 = c & 15;
            afragA[afrag_slot(row, kc8)] = aggp[(r0 + row)*16 + kc8];
        }
    } else {
        const u16x8* xbp = (const u16x8*)xb;
        for (int c = tid; c < 4096; c += 512){
            int mat = c >> 11, cc = c & 2047;
            int row = cc >> 4, kc8 = cc & 15;
            u16x8 v = (mat ? xbp : aggp)[(r0 + row)*16 + kc8];
            (mat ? afragX : afragA)[afrag_slot(row, kc8)] = v;
        }
    }
    __syncthreads();
    int w = tid >> 6, lane = tid & 63;
    int mtg = w >> 2;              // 0..1 -> rows mtg*64 .. mtg*64+63
    int cb  = (w & 3) * 32;        // col base within 128
    f32x16 acc0[6], acc1[6];
    #pragma unroll
    for (int t = 0; t < 6; t++){ acc0[t] = (f32x16)0.f; acc1[t] = (f32x16)0.f; }
    const u16x8* bi = (const u16x8*)wihb;
    const u16x8* bh = (const u16x8*)whhb;
    int kh = lane >> 5;
    int ncol = cb + (lane & 31);
    #pragma unroll
    for (int kc = 0; kc < 8; kc++){
        int lx = lane ^ kc;
        u16x8 aA0 = afragA[((2*mtg+0)*8 + kc)*64 + lx];
        u16x8 aA1 = afragA[((2*mtg+1)*8 + kc)*64 + lx];
        u16x8 aX0 = afragX[((2*mtg+0)*8 + kc)*64 + lx];
        u16x8 aX1 = afragX[((2*mtg+1)*8 + kc)*64 + lx];
        #pragma unroll
        for (int g3 = 0; g3 < 3; g3++){
            int n = g3*128 + ncol;
            u16x8 b1 = bi[n*16 + kc*2 + kh];
            u16x8 b2 = bh[n*16 + kc*2 + kh];
            acc0[g3]   = __builtin_amdgcn_mfma_f32_32x32x16_bf16(
                __builtin_bit_cast(bf16x8, aA0), __builtin_bit_cast(bf16x8, b1), acc0[g3], 0,0,0);
            acc1[g3]   = __builtin_amdgcn_mfma_f32_32x32x16_bf16(
                __builtin_bit_cast(bf16x8, aA1), __builtin_bit_cast(bf16x8, b1), acc1[g3], 0,0,0);
            acc0[3+g3] = __builtin_amdgcn_mfma_f32_32x32x16_bf16(
                __builtin_bit_cast(bf16x8, aX0), __builtin_bit_cast(bf16x8, b2), acc0[3+g3], 0,0,0);
            acc1[3+g3] = __builtin_amdgcn_mfma_f32_32x32x16_bf16(
                __builtin_bit_cast(bf16x8, aX1), __builtin_bit_cast(bf16x8, b2), acc1[3+g3], 0,0,0);
        }
    }
    int col = cb + (lane & 31);
    float bir = bih[col], biz = bih[col+128], bin = bih[col+256];
    float bhr = bhh[col], bhz = bhh[col+128], bhn = bhh[col+256];
    int kc8c = col >> 3, elc = col & 7;
    #pragma unroll
    for (int mt2 = 0; mt2 < 2; mt2++){
        const f32x16* ac = mt2 ? acc1 : acc0;
        #pragma unroll
        for (int r = 0; r < 16; r++){
            int row = mtg*64 + mt2*32 + (r&3) + 8*(r>>2) + 4*kh;
            u16x8 xv = afragX[afrag_slot(row, kc8c)];
            float xo = bf2f(((const u16*)&xv)[elc]);
            float rr  = sigf(ac[0][r] + bir + ac[3][r] + bhr);
            float zz  = sigf(ac[1][r] + biz + ac[4][r] + bhz);
            float nn_ = tanh_f(ac[2][r] + bin + rr*(ac[5][r] + bhn));
            float xn  = (1.f - zz)*nn_ + zz*xo;
            xb[(size_t)(r0 + row)*DIM + col] = f2bf(xn);
        }
    }
}

// ---------------------------------------------------------------------------
// FUSED transdim + attention, with active-concept compaction and 4-wide
// chunking (gg-row LDS reads amortized over 4 concepts; 3 barriers/chunk).
__global__ void __launch_bounds__(256)
k_attention(const u16* __restrict__ xb, const u16* __restrict__ twb,
            const float* __restrict__ cemb, const float* __restrict__ cid,
            const float* __restrict__ conc, const float* __restrict__ curres,
            float* __restrict__ lstm_in){
    int g = blockIdx.x; int tid = threadIdx.x;
    int lane = tid & 63, wv = tid >> 6;
    __shared__ __align__(16) unsigned char smem_raw[57344];  // x-frags, later gg
    __shared__ float ce_s[CP1N];
    __shared__ float sc4[4][256];
    __shared__ float wredA[4][4];
    __shared__ float wredB[4][4];
    __shared__ float part4[4][4][DCN];
    __shared__ float oacc[DCN];
    __shared__ float num_s;
    __shared__ int actv[CP1N];
    __shared__ int nact_s;
    u16x8* afrag = (u16x8*)smem_raw;
    float* gg    = (float*)smem_raw;     // 200*65*4 = 52000 B <= 57344
    const u16x8* xg = (const u16x8*)(xb + (size_t)g*NNODE*DIM);
    for (int c = tid; c < 3584; c += 256){
        int row = c >> 4, kc8 = c & 15;
        u16x8 v = {};
        if (row < NNODE) v = xg[row*16 + kc8];
        afrag[afrag_slot(row, kc8)] = v;
    }
    if (tid == 0) nact_s = 0;
    if (tid < CP1N) ce_s[tid] = cemb[(size_t)g*CP1N + tid];
    if (tid < DCN) oacc[tid] = 0.f;
    {
        float v = (tid < CP1N) ? cid[(size_t)g*CP1N + tid] : 0.f;
        #pragma unroll
        for (int m2 = 32; m2; m2 >>= 1) v += __shfl_xor(v, m2);
        if (lane == 0) wredA[wv][0] = v;
    }
    __syncthreads();
    if (tid == 0){
        float nm = wredA[0][0]+wredA[1][0]+wredA[2][0]+wredA[3][0];
        num_s = (nm == 0.f) ? 1.f : nm;
    }
    if (tid < CP1N && ce_s[tid] != 0.f){
        int p = atomicAdd(&nact_s, 1);
        actv[p] = tid;
    }
    // MFMA phase: wave wv -> col-tile ct = wv&1; row-tiles tb..tb+ntile-1
    {
        int ct = wv & 1, rh = wv >> 1;
        int tb = rh ? 4 : 0;
        int ntile = rh ? 3 : 4;          // wave-uniform
        int m = lane & 31, kh = lane >> 5;
        f32x16 acc[4];
        #pragma unroll
        for (int t = 0; t < 4; t++) acc[t] = (f32x16)0.f;
        const u16x8* tp = (const u16x8*)twb;
        #pragma unroll
        for (int kc = 0; kc < 8; kc++){
            u16x8 b = tp[(ct*32 + m)*16 + kc*2 + kh];
            #pragma unroll
            for (int t = 0; t < 4; t++){
                if (t < ntile){
                    u16x8 a = afrag[((tb+t)*8 + kc)*64 + (lane ^ kc)];
                    acc[t] = __builtin_amdgcn_mfma_f32_32x32x16_bf16(
                        __builtin_bit_cast(bf16x8, a), __builtin_bit_cast(bf16x8, b), acc[t], 0,0,0);
                }
            }
        }
        __syncthreads();   // afrag reads + actv build done before gg overwrite
        #pragma unroll
        for (int t = 0; t < 4; t++){
            if (t < ntile){
                #pragma unroll
                for (int r = 0; r < 16; r++){
                    int row = (tb+t)*32 + (r&3) + 8*(r>>2) + 4*kh;
                    int col = ct*32 + m;
                    if (row < NNODE) gg[row*65 + col] = acc[t][r];
                }
            }
        }
    }
    __syncthreads();
    int nact = nact_s;
    for (int ci = 0; ci < nact; ci += 4){
        int i0 = actv[ci];
        int i1 = actv[(ci+1 < nact) ? ci+1 : nact-1];
        int i2 = actv[(ci+2 < nact) ? ci+2 : nact-1];
        int i3 = actv[(ci+3 < nact) ? ci+3 : nact-1];
        float ce0 = ce_s[i0], ce1 = ce_s[i1], ce2 = ce_s[i2], ce3 = ce_s[i3];
        const float* q0 = conc + i0*DCN;
        const float* q1 = conc + i1*DCN;
        const float* q2 = conc + i2*DCN;
        const float* q3 = conc + i3*DCN;
        float s0=-1e30f, s1=-1e30f, s2=-1e30f, s3=-1e30f;
        if (tid < NNODE){
            float a0=0.f,a1=0.f,a2=0.f,a3=0.f;
            const float* gr_ = &gg[tid*65];
            #pragma unroll 8
            for (int d = 0; d < DCN; d++){
                float gv = gr_[d];
                a0 += q0[d]*gv; a1 += q1[d]*gv; a2 += q2[d]*gv; a3 += q3[d]*gv;
            }
            s0 = ce0*a0; s1 = ce1*a1; s2 = ce2*a2; s3 = ce3*a3;
        }
        float m0=s0, m1=s1, m2=s2, m3=s3;
        #pragma unroll
        for (int mk = 32; mk; mk >>= 1){
            m0 = fmaxf(m0, __shfl_xor(m0, mk));
            m1 = fmaxf(m1, __shfl_xor(m1, mk));
            m2 = fmaxf(m2, __shfl_xor(m2, mk));
            m3 = fmaxf(m3, __shfl_xor(m3, mk));
        }
        if (lane == 0){ wredA[wv][0]=m0; wredA[wv][1]=m1; wredA[wv][2]=m2; wredA[wv][3]=m3; }
        __syncthreads();                                    // barrier 1
        float mx0 = fmaxf(fmaxf(wredA[0][0],wredA[1][0]), fmaxf(wredA[2][0],wredA[3][0]));
        float mx1 = fmaxf(fmaxf(wredA[0][1],wredA[1][1]), fmaxf(wredA[2][1],wredA[3][1]));
        float mx2 = fmaxf(fmaxf(wredA[0][2],wredA[1][2]), fmaxf(wredA[2][2],wredA[3][2]));
        float mx3 = fmaxf(fmaxf(wredA[0][3],wredA[1][3]), fmaxf(wredA[2][3],wredA[3][3]));
        float e0 = (tid < NNODE) ? fexp2(LOG2E*(s0-mx0)) : 0.f;
        float e1 = (tid < NNODE) ? fexp2(LOG2E*(s1-mx1)) : 0.f;
        float e2 = (tid < NNODE) ? fexp2(LOG2E*(s2-mx2)) : 0.f;
        float e3 = (tid < NNODE) ? fexp2(LOG2E*(s3-mx3)) : 0.f;
        sc4[0][tid]=e0; sc4[1][tid]=e1; sc4[2][tid]=e2; sc4[3][tid]=e3;
        float u0=e0,u1=e1,u2=e2,u3=e3;
        #pragma unroll
        for (int mk = 32; mk; mk >>= 1){
            u0 += __shfl_xor(u0, mk);
            u1 += __shfl_xor(u1, mk);
            u2 += __shfl_xor(u2, mk);
            u3 += __shfl_xor(u3, mk);
        }
        if (lane == 0){ wredB[wv][0]=u0; wredB[wv][1]=u1; wredB[wv][2]=u2; wredB[wv][3]=u3; }
        __syncthreads();                                    // barrier 2
        float inv0 = ce0 / (wredB[0][0]+wredB[1][0]+wredB[2][0]+wredB[3][0]);
        float inv1 = (ci+1 < nact) ? ce1 / (wredB[0][1]+wredB[1][1]+wredB[2][1]+wredB[3][1]) : 0.f;
        float inv2 = (ci+2 < nact) ? ce2 / (wredB[0][2]+wredB[1][2]+wredB[2][2]+wredB[3][2]) : 0.f;
        float inv3 = (ci+3 < nact) ? ce3 / (wredB[0][3]+wredB[1][3]+wredB[2][3]+wredB[3][3]) : 0.f;
        float pa0=0.f, pa1=0.f, pa2=0.f, pa3=0.f;
        for (int n = wv; n < NNODE; n += 4){
            float gv = gg[n*65 + lane];
            pa0 += sc4[0][n]*gv; pa1 += sc4[1][n]*gv;
            pa2 += sc4[2][n]*gv; pa3 += sc4[3][n]*gv;
        }
        part4[wv][0][lane]=pa0; part4[wv][1][lane]=pa1;
        part4[wv][2][lane]=pa2; part4[wv][3][lane]=pa3;
        __syncthreads();                                    // barrier 3
        if (tid < DCN){
            float t0 = part4[0][0][tid]+part4[1][0][tid]+part4[2][0][tid]+part4[3][0][tid];
            float t1 = part4[0][1][tid]+part4[1][1][tid]+part4[2][1][tid]+part4[3][1][tid];
            float t2 = part4[0][2][tid]+part4[1][2][tid]+part4[2][2][tid]+part4[3][2][tid];
            float t3 = part4[0][3][tid]+part4[1][3][tid]+part4[2][3][tid]+part4[3][3][tid];
            oacc[tid] += inv0*t0 + inv1*t1 + inv2*t2 + inv3*t3;
        }
    }
    __syncthreads();
    if (tid < FEATN){
        float v;
        if      (tid < CP1N)       v = ce_s[tid];
        else if (tid < CP1N+DCN)   v = oacc[tid-CP1N] / num_s;
        else                       v = curres[(size_t)g*2 + (tid-CP1N-DCN)];
        lstm_in[(size_t)g*FEATN + tid] = v;
    }
}

// ---------------------------------------------------------------------------
// gi_all = lstm_in @ Wih^T + (bih + bhh)    (800 x 1024, K=177)
__global__ void __launch_bounds__(256)
k_gi(const float* __restrict__ lstm_in, const float* __restrict__ wihT,
     const float* __restrict__ bih, const float* __restrict__ bhh, float* __restrict__ gi){
    int rb = blockIdx.x;   // 100 blocks of 8 rows
    int jb = blockIdx.y;   // 4
    int tid = threadIdx.x;
    __shared__ float in_s[8][FEATN];
    for (int i = tid; i < 8*FEATN; i += 256){ int r = i/FEATN, k = i%FEATN; in_s[r][k] = lstm_in[((size_t)rb*8+r)*FEATN + k]; }
    __syncthreads();
    int j = jb*256 + tid;
    float acc[8];
    #pragma unroll
    for (int i = 0; i < 8; i++) acc[i] = 0.f;
    for (int k = 0; k < FEATN; k++){
        float w = wihT[(size_t)k*1024 + j];
        #pragma unroll
        for (int i = 0; i < 8; i++) acc[i] += in_s[i][k] * w;
    }
    float b = bih[j] + bhh[j];
    #pragma unroll
    for (int i = 0; i < 8; i++) gi[((size_t)rb*8+i)*1024 + j] = acc[i] + b;
}

// ---------------------------------------------------------------------------
// Sequential LSTM (R7 structure). 104 bf16-pairs/thread in VGPRs + 24 pairs in
// LDS as uint4; gates via LDS, 2 barriers/step.
static const int WREG = 104;
static const int WL4  = 6;    // 24 pairs = 6 uint4 groups (pairs 104..127)

__global__ void __launch_bounds__(1024)
__attribute__((amdgpu_waves_per_eu(4,4)))
k_lstm(const float* __restrict__ gi, const unsigned* __restrict__ whhP, float* __restrict__ out){
    int b = blockIdx.x; int tid = threadIdx.x;
    __shared__ uint4 ldsw4[WL4][1024];       // 96 KB
    __shared__ float gates[1024];
    __shared__ __align__(8) u16 h16[HID];    // packed bf16 h, read as u32 pairs
    unsigned wreg[WREG];
    #pragma unroll
    for (int i = 0; i < WREG; i++) wreg[i] = whhP[(size_t)i*1024 + tid];
    #pragma unroll
    for (int q = 0; q < WL4; q++){
        uint4 v;
        v.x = whhP[(size_t)(WREG + 4*q + 0)*1024 + tid];
        v.y = whhP[(size_t)(WREG + 4*q + 1)*1024 + tid];
        v.z = whhP[(size_t)(WREG + 4*q + 2)*1024 + tid];
        v.w = whhP[(size_t)(WREG + 4*q + 3)*1024 + tid];
        ldsw4[q][tid] = v;
    }
    if (tid < 128) ((unsigned*)h16)[tid] = 0u;
    float c_reg = 0.f;
    int lane = tid & 63;
    __syncthreads();
    float giv = gi[(size_t)b*SLN*1024 + tid];
    for (int t = 0; t < SLN; t++){
        unsigned hv0 = ((const unsigned*)h16)[lane];
        unsigned hv1 = ((const unsigned*)h16)[64 + lane];
        float acc0 = giv, acc1 = 0.f;
        if (t+1 < SLN) giv = gi[((size_t)b*SLN + t + 1)*1024 + tid];
        #pragma unroll
        for (int p = 0; p < 64; p += 2){
            unsigned hpa = (unsigned)__builtin_amdgcn_readlane((int)hv0, p);
            unsigned hpb = (unsigned)__builtin_amdgcn_readlane((int)hv0, p+1);
            acc0 = dot2bf(wreg[p],   hpa, acc0);
            acc1 = dot2bf(wreg[p+1], hpb, acc1);
        }
        #pragma unroll
        for (int p = 64; p < WREG; p += 2){
            unsigned hpa = (unsigned)__builtin_amdgcn_readlane((int)hv1, p - 64);
            unsigned hpb = (unsigned)__builtin_amdgcn_readlane((int)hv1, p - 63);
            acc0 = dot2bf(wreg[p],   hpa, acc0);
            acc1 = dot2bf(wreg[p+1], hpb, acc1);
        }
        #pragma unroll
        for (int q = 0; q < WL4; q++){
            uint4 wv = ldsw4[q][tid];
            int base = WREG + 4*q - 64;
            unsigned h0 = (unsigned)__builtin_amdgcn_readlane((int)hv1, base + 0);
            unsigned h1 = (unsigned)__builtin_amdgcn_readlane((int)hv1, base + 1);
            unsigned h2 = (unsigned)__builtin_amdgcn_readlane((int)hv1, base + 2);
            unsigned h3 = (unsigned)__builtin_amdgcn_readlane((int)hv1, base + 3);
            acc0 = dot2bf(wv.x, h0, acc0);
            acc1 = dot2bf(wv.y, h1, acc1);
            acc0 = dot2bf(wv.z, h2, acc0);
            acc1 = dot2bf(wv.w, h3, acc1);
        }
        gates[tid] = acc0 + acc1;
        __syncthreads();
        if (tid < HID){
            float i_ = sigf(gates[tid]);
            float f_ = sigf(gates[tid+256]);
            float g_ = tanh_f(gates[tid+512]);
            float o_ = sigf(gates[tid+768]);
            c_reg = f_*c_reg + i_*g_;
            float h = o_*tanh_f(c_reg);
            out[((size_t)b*SLN + t)*HID + tid] = h;
            h16[tid] = f2bf(h);
        }
        __syncthreads();
    }
}

// ---------------------------------------------------------------------------
// pred + masked BCE per row; outputs sigmoid(fp), ft; atomics for loss sums.
__global__ void __launch_bounds__(128)
k_final(const float* __restrict__ lstm_out, const float* __restrict__ pw, const float* __restrict__ pb,
        const float* __restrict__ tc, const float* __restrict__ result,
        float* __restrict__ out, float* __restrict__ lacc){
    int row = blockIdx.x; int tid = threadIdx.x;
    __shared__ __align__(16) float h_s[HID];
    __shared__ float redv[128], redn[128];
    h_s[tid]       = lstm_out[(size_t)row*HID + tid];
    h_s[tid + 128] = lstm_out[(size_t)row*HID + tid + 128];
    __syncthreads();
    float v = 0.f, n = 0.f;
    if (tid < CP1N){
        float acc = pb[tid];
        const float4* wr = (const float4*)(pw + (size_t)tid*HID);
        const float4* hp = (const float4*)h_s;
        #pragma unroll 8
        for (int k4 = 0; k4 < 64; k4++){
            float4 w = wr[k4]; float4 h4 = hp[k4];
            acc += h4.x*w.x + h4.y*w.y + h4.z*w.z + h4.w*w.w;
        }
        float t = tc[(size_t)row*CP1N + tid];
        v = acc*t; n = t;
    }
    redv[tid] = v; redn[tid] = n;
    __syncthreads();
    for (int s = 64; s > 0; s >>= 1){
        if (tid < s){ redv[tid] += redv[tid+s]; redn[tid] += redn[tid+s]; }
        __syncthreads();
    }
    if (tid == 0){
        float nc = redn[0];
        bool mask = nc > 0.f;
        float fp = redv[0] / (mask ? nc : 1.f);
        float ft = result[row];
        float bce = fmaxf(fp, 0.f) - fp*ft + log1pf(expf(-fabsf(fp)));
        out[1 + row]      = 1.f/(1.f + expf(-fp));
        out[1 + GN + row] = ft;
        if (mask){ atomicAdd(&lacc[0], bce); atomicAdd(&lacc[1], 1.f); }
    }
}

__global__ void k_loss_final(const float* __restrict__ lacc, float* __restrict__ out){
    out[0] = lacc[0] / fmaxf(lacc[1], 1.f);
}

// ---------------------------------------------------------------------------
extern "C" void kernel_launch(void* const* d_in, const int* in_sizes, int n_in,
                              void* d_out, int out_size, void* d_ws, size_t ws_size,
                              hipStream_t stream) {
    const float* c_id        = (const float*)d_in[1];
    const int*   node_id     = (const int*)  d_in[2];
    const int*   edge        = (const int*)  d_in[3];
    const int*   etype       = (const int*)  d_in[4];
    const float* target_c    = (const float*)d_in[5];
    const float* result      = (const float*)d_in[6];
    const float* c_embed     = (const float*)d_in[7];
    const float* cur_result  = (const float*)d_in[8];
    const float* node_emb_w  = (const float*)d_in[9];
    const float* edge_emb_w  = (const float*)d_in[10];
    const float* ggnn_w      = (const float*)d_in[11];
    const float* gru_w_ih    = (const float*)d_in[12];
    const float* gru_w_hh    = (const float*)d_in[13];
    const float* gru_b_ih    = (const float*)d_in[14];
    const float* gru_b_hh    = (const float*)d_in[15];
    const float* transdim_w  = (const float*)d_in[16];
    const float* concept     = (const float*)d_in[17];
    const float* lstm_w_ih   = (const float*)d_in[18];
    const float* lstm_w_hh   = (const float*)d_in[19];
    const float* lstm_b_ih   = (const float*)d_in[20];
    const float* lstm_b_hh   = (const float*)d_in[21];
    const float* pred_w      = (const float*)d_in[22];
    const float* pred_b      = (const float*)d_in[23];
    float* out = (float*)d_out;

    char* ws = (char*)d_ws;
    size_t off = 0;
    auto alloc = [&](size_t bytes) -> void* {
        void* p = ws + off;
        off += (bytes + 255) & ~(size_t)255;
        return p;
    };
    u16*      xb       = (u16*)     alloc((size_t)MROW*DIM*2);
    u16*      aggb     = (u16*)     alloc((size_t)MROW*DIM*2);
    int*      csr_src  = (int*)     alloc((size_t)GN*NEDGE*4);
    float*    csr_w    = (float*)   alloc((size_t)GN*NEDGE*4);
    int*      csr_off  = (int*)     alloc((size_t)GN*(NNODE+1)*4);
    float*    lstm_in  = (float*)   alloc((size_t)GN*FEATN*4);
    float*    gi       = (float*)   alloc((size_t)GN*1024*4);
    unsigned* whhP     = (unsigned*)alloc((size_t)128*1024*4);
    float*    wihT     = (float*)   alloc((size_t)FEATN*1024*4);
    float*    lstm_out = (float*)   alloc((size_t)GN*HID*4);
    u16*      wihb     = (u16*)     alloc((size_t)384*128*2);
    u16*      whhb     = (u16*)     alloc((size_t)384*128*2);
    u16*      gwTb     = (u16*)     alloc((size_t)4*128*128*2);
    u16*      twb      = (u16*)     alloc((size_t)DCN*DIM*2);
    float*    lacc     = (float*)   alloc(256);

    hipMemsetAsync(lacc, 0, 8, stream);
    {
        int total = 128*1024 + FEATN*1024;
        k_transpose_w<<<(total + 255)/256, 256, 0, stream>>>(lstm_w_hh, lstm_w_ih, whhP, wihT);
    }
    k_convert_w<<<672, 256, 0, stream>>>(gru_w_ih, gru_w_hh, ggnn_w, transdim_w, wihb, whhb, gwTb, twb);
    k_build_csr<<<GN, 256, 0, stream>>>(edge, etype, edge_emb_w, csr_src, csr_w, csr_off);
    for (int l = 0; l < 4; l++){
        k_mm_scatter<<<GN, 256, 0, stream>>>(xb, gwTb + (size_t)l*DIM*DIM,
                                             csr_src, csr_w, csr_off, aggb,
                                             (const float4*)node_emb_w, node_id, l == 0);
        k_gru_mfma<<<MROW/128, 512, 0, stream>>>(xb, aggb, wihb, whhb, gru_b_ih, gru_b_hh,
                                                 (const float4*)node_emb_w, node_id, l == 0);
    }
    k_attention<<<GN, 256, 0, stream>>>(xb, twb, c_embed, c_id, concept, cur_result, lstm_in);
    k_gi<<<dim3(100, 4), 256, 0, stream>>>(lstm_in, wihT, lstm_b_ih, lstm_b_hh, gi);
    k_lstm<<<BSZ, 1024, 0, stream>>>(gi, whhP, lstm_out);
    k_final<<<GN, 128, 0, stream>>>(lstm_out, pred_w, pred_b, target_c, result, out, lacc);
    k_loss_final<<<1, 1, 0, stream>>>(lacc, out);
}